// Round 13
// baseline (327.999 us; speedup 1.0000x reference)
//
#include <hip/hip_runtime.h>
#include <math.h>

typedef unsigned short u16;
typedef unsigned int u32;
typedef __attribute__((ext_vector_type(8))) short short8;
typedef __attribute__((ext_vector_type(4))) float f32x4;

// Problem constants
#define B_   128
#define L_   2048
#define C_   64
#define P_   720
#define P2_  1440
#define NPAD 1536     // proj cols padded to multiple of 128 (interleaved a/g)
#define NFFT 4096
#define NROW (B_*C_)  // 8192
#define TCHUNK 16     // time chunks for stats phase 1

// prep-kernel block ranges (longest blocks first)
#define PREP_SSMK   512
#define PREP_STATS1 2048
#define PREP_NB     (PREP_SSMK + PREP_STATS1 + 1 + (NPAD * L_) / 256)
// packfftk ranges
#define PF_PACK  4096
#define PF_FFTK  64
#define PF_NB    (PF_PACK + PF_FFTK + 32)

// global -> LDS direct staging, 16 B per lane; LDS dest = uniform base + lane*16
#define GLOAD_LDS16(g, l) __builtin_amdgcn_global_load_lds( \
    (const __attribute__((address_space(1))) unsigned int*)(g), \
    (__attribute__((address_space(3))) unsigned int*)(l), 16, 0, 0)

__device__ __forceinline__ u16 f2bf(float f) {
  union { float f; unsigned u; } x; x.f = f;
  unsigned r = x.u + 0x7fffu + ((x.u >> 16) & 1u);
  return (u16)(r >> 16);
}
__device__ __forceinline__ float bf2f_lo(u32 v) {
  union { unsigned u; float f; } x; x.u = v << 16; return x.f;
}
__device__ __forceinline__ float bf2f_hi(u32 v) {
  union { unsigned u; float f; } x; x.u = v & 0xffff0000u; return x.f;
}

__device__ __forceinline__ float2 cmul(float2 a, float2 b) {
  return make_float2(a.x * b.x - a.y * b.y, a.x * b.y + a.y * b.x);
}
__device__ __forceinline__ float2 cadd(float2 a, float2 b) { return make_float2(a.x + b.x, a.y + b.y); }
__device__ __forceinline__ float2 csub(float2 a, float2 b) { return make_float2(a.x - b.x, a.y - b.y); }

#define CSWAP(i, j) { float2 tt = a[i]; a[i] = a[j]; a[j] = tt; }

// ===================== 16-point DFT in registers =====================
template<bool INV, bool HZ>
__device__ __forceinline__ void dft16(float2 a[16]) {
  const float S  = INV ? 1.f : -1.f;
  const float c1 = 0.9238795325112867f, s1 = 0.3826834323650898f, q2 = 0.7071067811865476f;
  const float2 W1 = make_float2( c1, S * s1), W2 = make_float2( q2, S * q2), W3 = make_float2( s1, S * c1);
  const float2 W5 = make_float2(-s1, S * c1), W6 = make_float2(-q2, S * q2), W7 = make_float2(-c1, S * s1);
  if (HZ) {
    a[8]  = a[0];
    a[9]  = cmul(a[1], W1);
    a[10] = cmul(a[2], W2);
    a[11] = cmul(a[3], W3);
    a[12] = make_float2(-S * a[4].y, S * a[4].x);
    a[13] = cmul(a[5], W5);
    a[14] = cmul(a[6], W6);
    a[15] = cmul(a[7], W7);
  } else {
    float2 t;
    t = csub(a[0], a[8]);  a[0] = cadd(a[0], a[8]);  a[8]  = t;
    t = csub(a[1], a[9]);  a[1] = cadd(a[1], a[9]);  a[9]  = cmul(t, W1);
    t = csub(a[2], a[10]); a[2] = cadd(a[2], a[10]); a[10] = cmul(t, W2);
    t = csub(a[3], a[11]); a[3] = cadd(a[3], a[11]); a[11] = cmul(t, W3);
    t = csub(a[4], a[12]); a[4] = cadd(a[4], a[12]); a[12] = make_float2(-S * t.y, S * t.x);
    t = csub(a[5], a[13]); a[5] = cadd(a[5], a[13]); a[13] = cmul(t, W5);
    t = csub(a[6], a[14]); a[6] = cadd(a[6], a[14]); a[14] = cmul(t, W6);
    t = csub(a[7], a[15]); a[7] = cadd(a[7], a[15]); a[15] = cmul(t, W7);
  }
#pragma unroll
  for (int h = 0; h < 16; h += 8) {
    float2 t;
    t = csub(a[h+0], a[h+4]); a[h+0] = cadd(a[h+0], a[h+4]); a[h+4] = t;
    t = csub(a[h+1], a[h+5]); a[h+1] = cadd(a[h+1], a[h+5]); a[h+5] = cmul(t, W2);
    t = csub(a[h+2], a[h+6]); a[h+2] = cadd(a[h+2], a[h+6]); a[h+6] = make_float2(-S * t.y, S * t.x);
    t = csub(a[h+3], a[h+7]); a[h+3] = cadd(a[h+3], a[h+7]); a[h+7] = cmul(t, W6);
  }
#pragma unroll
  for (int q = 0; q < 16; q += 4) {
    float2 t;
    t = csub(a[q+0], a[q+2]); a[q+0] = cadd(a[q+0], a[q+2]); a[q+2] = t;
    t = csub(a[q+1], a[q+3]); a[q+1] = cadd(a[q+1], a[q+3]); a[q+3] = make_float2(-S * t.y, S * t.x);
  }
#pragma unroll
  for (int p = 0; p < 16; p += 2) {
    float2 t = csub(a[p], a[p+1]); a[p] = cadd(a[p], a[p+1]); a[p+1] = t;
  }
  CSWAP(1, 8); CSWAP(2, 4); CSWAP(3, 12); CSWAP(5, 10); CSWAP(7, 14); CSWAP(11, 13);
}

// twiddle apply: a[k] *= w1^k. Powers via binary tree (depth 4) -> independent applies (ILP).
__device__ __forceinline__ void twchain(float2 a[16], float2 w1) {
  float2 w2 = cmul(w1, w1);
  float2 w3 = cmul(w2, w1);
  float2 w4 = cmul(w2, w2);
  float2 w5 = cmul(w3, w2);
  float2 w6 = cmul(w3, w3);
  float2 w7 = cmul(w4, w3);
  float2 w8 = cmul(w4, w4);
  float2 w9 = cmul(w5, w4);
  float2 w10 = cmul(w5, w5);
  float2 w11 = cmul(w6, w5);
  float2 w12 = cmul(w6, w6);
  float2 w13 = cmul(w7, w6);
  float2 w14 = cmul(w7, w7);
  float2 w15 = cmul(w8, w7);
  a[1]  = cmul(a[1],  w1);  a[2]  = cmul(a[2],  w2);  a[3]  = cmul(a[3],  w3);
  a[4]  = cmul(a[4],  w4);  a[5]  = cmul(a[5],  w5);  a[6]  = cmul(a[6],  w6);
  a[7]  = cmul(a[7],  w7);  a[8]  = cmul(a[8],  w8);  a[9]  = cmul(a[9],  w9);
  a[10] = cmul(a[10], w10); a[11] = cmul(a[11], w11); a[12] = cmul(a[12], w12);
  a[13] = cmul(a[13], w13); a[14] = cmul(a[14], w14); a[15] = cmul(a[15], w15);
}

// ===================== swizzled LDS transposes (FFT) =====================
__device__ __forceinline__ void lds_wA(float2* X, const float2 r[16], int tid) {
  int base = (tid & 15) * 16 + ((tid >> 4) ^ ((tid & 7) << 1));
#pragma unroll
  for (int i = 0; i < 16; ++i) X[base + i * 256] = r[i];
}
__device__ __forceinline__ void lds_wB(float2* X, const float2 r[16], int tid) {
#pragma unroll
  for (int i = 0; i < 16; ++i)
    X[((tid & 0xF0) + i) * 16 + ((tid & 15) ^ ((i & 7) << 1))] = r[i];
}
__device__ __forceinline__ void lds_rd(const float2* X, float2 r[16], int tid) {
  const float4* X4 = (const float4*)X;
#pragma unroll
  for (int p = 0; p < 8; ++p) {
    float4 v = X4[tid * 8 + (p ^ (tid & 7))];
    r[2 * p]     = make_float2(v.x, v.y);
    r[2 * p + 1] = make_float2(v.z, v.w);
  }
}

__device__ __forceinline__ void fft_fwd_hz(float2 r[16], float2* X, int tid, const float2* twg) {
  dft16<false, true>(r);
  twchain(r, twg[tid]);
  lds_wA(X, r, tid);
  __syncthreads();
  lds_rd(X, r, tid);
  dft16<false, false>(r);
  twchain(r, twg[(tid & 15) << 4]);
  __syncthreads();
  lds_wB(X, r, tid);
  __syncthreads();
  lds_rd(X, r, tid);
  dft16<false, false>(r);
}

__device__ __forceinline__ void fft_inv(float2 r[16], float2* X, int tid, const float2* twg) {
  dft16<true, false>(r);
  __syncthreads();
  lds_wB(X, r, tid);
  __syncthreads();
  lds_rd(X, r, tid);
  float2 wb = twg[(tid & 15) << 4];
  twchain(r, make_float2(wb.x, -wb.y));
  dft16<true, false>(r);
  __syncthreads();
  lds_wA(X, r, tid);
  __syncthreads();
  lds_rd(X, r, tid);
  float2 wa = twg[tid];
  twchain(r, make_float2(wa.x, -wa.y));
  dft16<true, false>(r);
}

// ===================== fused prep: ssmk + stats1 + twfill + wconv =====================
__global__ __launch_bounds__(256) void k_prep(const float* __restrict__ pw, u16* __restrict__ wb,
                                              const float* __restrict__ u, float* __restrict__ ps,
                                              float* __restrict__ pq,
                                              const float* __restrict__ Cp, const float* __restrict__ ldt,
                                              const float* __restrict__ lAr, const float* __restrict__ Aim,
                                              float2* __restrict__ kz, float2* __restrict__ tw) {
  __shared__ float4 sb[16][16], qb[16][16];
  int blk = blockIdx.x, tid = threadIdx.x;
  if (blk < PREP_SSMK) {
    // ---- ssmk (longest blocks first) ----
    int gid = blk * 256 + tid;   // 64*2048
    int h = gid & 2047;
    int j = gid >> 11;
    float dt = expf(ldt[h]);
    float accx = 0.f;
    float Ar0 = 0.f;
    for (int n = 0; n < 64; ++n) {
      float Ar = -expf(lAr[h * 64 + n]);
      float Ai = Aim[h * 64 + n];
      if (n == 0) Ar0 = Ar;
      float dAr = Ar * dt, dAi = Ai * dt;
      float er = expf(dAr);
      float s1, c1; sincosf(dAi, &s1, &c1);
      float emr = er * c1 - 1.0f, emi = er * s1;
      float inv = 1.0f / (Ar * Ar + Ai * Ai);
      float qr = (emr * Ar + emi * Ai) * inv;
      float qi = (emi * Ar - emr * Ai) * inv;
      float cr = Cp[(size_t)(h * 64 + n) * 2];
      float ci = Cp[(size_t)(h * 64 + n) * 2 + 1];
      float ccr = cr * qr - ci * qi;
      float cci = cr * qi + ci * qr;
      float ej = expf(dAr * (float)j);
      float sj, cj; sincosf(dAi * (float)j, &sj, &cj);
      accx += ccr * (ej * cj) - cci * (ej * sj);
    }
    float K = 2.0f * accx;
    float K2 = 2.0f * K * (Ar0 * (float)j * dt);
    kz[(size_t)j * L_ + h] = make_float2(K2, -K);        // pack K2 - i*K
  } else if (blk < PREP_SSMK + PREP_STATS1) {
    // ---- stats1 ----
    int blk2 = blk - PREP_SSMK;          // b*TCHUNK + q
    int b = blk2 >> 4, q = blk2 & 15;
    int c4 = tid & 15, g = tid >> 4;     // 16 groups x 8 t-steps
    const float4* u4 = (const float4*)(u + ((size_t)b * L_ + q * 128) * C_);
    float4 s = make_float4(0.f, 0.f, 0.f, 0.f), sq = s;
#pragma unroll
    for (int i = 0; i < 8; ++i) {
      float4 v = u4[(size_t)(g + 16 * i) * 16 + c4];
      s.x += v.x; s.y += v.y; s.z += v.z; s.w += v.w;
      sq.x += v.x * v.x; sq.y += v.y * v.y; sq.z += v.z * v.z; sq.w += v.w * v.w;
    }
    sb[g][c4] = s; qb[g][c4] = sq;
    __syncthreads();
    if (g == 0) {
      float4 S = sb[0][c4], Q = qb[0][c4];
#pragma unroll
      for (int k = 1; k < 16; ++k) {
        float4 a = sb[k][c4], d = qb[k][c4];
        S.x += a.x; S.y += a.y; S.z += a.z; S.w += a.w;
        Q.x += d.x; Q.y += d.y; Q.z += d.z; Q.w += d.w;
      }
      ((float4*)ps)[blk2 * 16 + c4] = S;
      ((float4*)pq)[blk2 * 16 + c4] = Q;
    }
  } else if (blk == PREP_SSMK + PREP_STATS1) {
    // ---- twfill ----
    int k = tid;
    double ang = -2.0 * 3.14159265358979323846 * (double)k / 4096.0;
    tw[k] = make_float2((float)cos(ang), (float)sin(ang));
  } else {
    // ---- wconv: interleaved (a,g) proj rows -> bf16 ----
    size_t idx = (size_t)(blk - (PREP_SSMK + PREP_STATS1 + 1)) * 256 + tid;
    int n = (int)(idx >> 11);
    int k = (int)(idx & 2047);
    int q = n >> 1;
    float v = 0.f;
    if (q < P_) {
      int p = (n & 1) ? (P_ + q) : q;
      v = pw[(size_t)p * L_ + k];
    }
    wb[idx] = f2bf(v);
  }
}

// ===================== fused: packT (inline mv) + fftk + stats2(for gemm) =====================
__global__ __launch_bounds__(256) void k_packfftk(const float* __restrict__ u, const float* __restrict__ Wn,
                                                  const float* __restrict__ lv,
                                                  const float* __restrict__ ps, const float* __restrict__ pq,
                                                  u32* __restrict__ zu,
                                                  const float2* __restrict__ kz, const float2* __restrict__ twg,
                                                  float2* __restrict__ G, float4* __restrict__ mv) {
  __shared__ __align__(16) char smem[33280];
  int blk = blockIdx.x, tid = threadIdx.x;
  if (blk < PF_PACK) {
    // ---- packT with inline per-block mv recompute (bit-identical to stats2) ----
    int b = blk >> 5;
    int t0 = (blk & 31) << 6;
    float4* mvs = (float4*)smem;           // transient, first 1 KB
    if (tid < 64) {
      float S = 0.f, Q = 0.f;
#pragma unroll
      for (int q = 0; q < 16; ++q) {
        S += ps[(size_t)(b * 16 + q) * 64 + tid];
        Q += pq[(size_t)(b * 16 + q) * 64 + tid];
      }
      float mean = S * (1.0f / 2048.0f);
      float var = (Q - S * S * (1.0f / 2048.0f)) * (1.0f / 2047.0f) + 1e-5f;
      float sv = sqrtf(var);
      mvs[tid] = make_float4(mean, sv, 1.0f / sv, 0.0f);
    }
    __syncthreads();
    int c = tid & 63, r = tid >> 6;
    float4 m = mvs[c];
    float stdn = sqrtf(__expf(lv[0]));
    __syncthreads();                       // mvs reads done before tile overwrites
    float2 (*tile)[65] = (float2(*)[65])smem;
#pragma unroll
    for (int i = 0; i < 16; ++i) {
      int t = t0 + i * 4 + r;
      size_t idx = ((size_t)b * L_ + t) * C_ + c;
      float uu = (u[idx] - m.x) * m.z;
      float ww = Wn[idx] * stdn;
      tile[i * 4 + r][c] = make_float2(uu, ww);
    }
    __syncthreads();
    int t = tid & 63, cb = tid >> 6;
#pragma unroll
    for (int i = 0; i < 16; ++i) {
      int c2 = i * 4 + cb;
      float2 v = tile[t][c2];
      zu[((size_t)(b * C_ + c2)) * L_ + t0 + t] = ((u32)f2bf(v.y) << 16) | (u32)f2bf(v.x);
    }
  } else if (blk < PF_PACK + PF_FFTK) {
    // ---- fftk: G[j] = FFT(K2 - iK)/4096 ----
    float2* X = (float2*)smem;
    int j = blk - PF_PACK;
    float2 r[16];
#pragma unroll
    for (int n2 = 0; n2 < 8; ++n2) r[n2] = kz[(size_t)j * L_ + n2 * 256 + tid];
    fft_fwd_hz(r, X, tid, twg);
    const float sc = 1.0f / 4096.0f;
#pragma unroll
    for (int k0 = 0; k0 < 16; ++k0)
      G[(size_t)j * NFFT + k0 * 256 + tid] = make_float2(r[k0].x * sc, r[k0].y * sc);
  } else {
    // ---- stats2: mv for the gemm epilogue (consumed 2 kernels later) ----
    int gid = (blk - (PF_PACK + PF_FFTK)) * 256 + tid;   // 8192
    int b = gid >> 6, c = gid & 63;
    float S = 0.f, Q = 0.f;
#pragma unroll
    for (int q = 0; q < 16; ++q) {
      S += ps[(size_t)(b * 16 + q) * 64 + c];
      Q += pq[(size_t)(b * 16 + q) * 64 + c];
    }
    float mean = S * (1.0f / 2048.0f);
    float var = (Q - S * S * (1.0f / 2048.0f)) * (1.0f / 2047.0f) + 1e-5f;
    float sv = sqrtf(var);
    mv[gid] = make_float4(mean, sv, 1.0f / sv, 0.0f);
  }
}

// ===================== main conv per row: y = Re(IFFT(FFT(z) .* G)) + un*D =====================
__global__ __launch_bounds__(256) void k_fftmain(const u32* __restrict__ zu, const float2* __restrict__ twg,
                                                 const float2* __restrict__ G, const float* __restrict__ Dv,
                                                 u16* __restrict__ yT) {
  __shared__ float2 X[NFFT];
  int row = blockIdx.x;           // b*64 + j
  int j = row & 63;
  int tid = threadIdx.x;
  float2 r[16];
  float usav[8];
#pragma unroll
  for (int n2 = 0; n2 < 8; ++n2) {
    u32 v = zu[(size_t)row * L_ + n2 * 256 + tid];
    float uu = bf2f_lo(v), ww = bf2f_hi(v);
    r[n2] = make_float2(uu, ww);
    usav[n2] = uu;
  }
  fft_fwd_hz(r, X, tid, twg);
  const float2* Gj = G + (size_t)j * NFFT;
#pragma unroll
  for (int k0 = 0; k0 < 16; ++k0) r[k0] = cmul(r[k0], Gj[k0 * 256 + tid]);
  fft_inv(r, X, tid, twg);
#pragma unroll
  for (int n2 = 8; n2 < 16; ++n2) {
    int t = (n2 - 8) * 256 + tid;
    float yv = r[n2].x + usav[n2 - 8] * Dv[t];
    yT[(size_t)row * L_ + t] = f2bf(yv);
  }
}

// ===================== bf16 MFMA GEMM — 2-deep counted-vmcnt pipeline + fused GLU epilogue ===========
// C[M=8192][N=1536] = yT[M][K=2048] * Wb[N][K]^T, Wb cols interleaved (a,g) pairs.
// T3+T4 minimum: dbuf LDS staged via global_load_lds, raw s_barrier (no auto vmcnt drain),
// counted `s_waitcnt vmcnt(4)` waits only the oldest tile; 2 tiles always in flight.
__device__ __forceinline__ int lds_ix(int row, int slot) {
  return row * 32 + ((slot ^ ((row >> 1) & 3)) << 3);   // u16 units
}

__global__ __launch_bounds__(256) void k_gemm(const u16* __restrict__ A, const u16* __restrict__ B,
                                              const float* __restrict__ pb, const float4* __restrict__ mv,
                                              float* __restrict__ out) {
  __shared__ u16 As[2][128 * 32];
  __shared__ u16 Bs[2][128 * 32];
  __shared__ float ob[32 * 132];   // 16.9 KB epilogue staging
  const int K = L_;
  int tid = threadIdx.x;
  // bijective XCD swizzle: 768 blocks, 96 per XCD
  int bid = blockIdx.x;
  int swz = (bid & 7) * 96 + (bid >> 3);
  int bm = swz % 64, bn = swz / 64;
  int wave = tid >> 6, lane = tid & 63;
  int wm = (wave >> 1) << 6, wn = (wave & 1) << 6;
  int lr = lane & 15, lk = lane >> 4;
  // staging: wave w stages rows [w*32, w*32+32), 2 issues of 16 rows each.
  // LDS dest is LINEAR (base + lane*16). Read side uses lds_ix swizzle, so the
  // global SOURCE column is pre-swizzled (rule #21): col = (slot ^ sw(row))*8.
  // sw(row+16)==sw(row) since ((r+16)>>1)&3 == (r>>1)&3, so one scol serves both issues.
  int srow = wave * 32 + (lane >> 2);
  int sslot = lane & 3;
  int scol = (sslot ^ ((srow >> 1) & 3)) << 3;
  const u16* Ag = A + (size_t)(bm * 128 + srow) * K + scol;
  const u16* Bg = B + (size_t)(bn * 128 + srow) * K + scol;
  int woff = wave * 32 * 32;
  f32x4 acc[4][4] = {};
  // prologue: 2 tiles in flight (8 gload_lds)
  GLOAD_LDS16(Ag, &As[0][woff]);
  GLOAD_LDS16(Ag + (size_t)16 * K, &As[0][woff + 16 * 32]);
  GLOAD_LDS16(Bg, &Bs[0][woff]);
  GLOAD_LDS16(Bg + (size_t)16 * K, &Bs[0][woff + 16 * 32]);
  GLOAD_LDS16(Ag + 32, &As[1][woff]);
  GLOAD_LDS16(Ag + 32 + (size_t)16 * K, &As[1][woff + 16 * 32]);
  GLOAD_LDS16(Bg + 32, &Bs[1][woff]);
  GLOAD_LDS16(Bg + 32 + (size_t)16 * K, &Bs[1][woff + 16 * 32]);
  int cur = 0;
  for (int kt = 0; kt < K; kt += 32) {
    if (kt + 32 < K) {
      asm volatile("s_waitcnt vmcnt(4)" ::: "memory");   // oldest tile landed (per-wave)
    } else {
      asm volatile("s_waitcnt vmcnt(0)" ::: "memory");   // last tile: drain
    }
    __builtin_amdgcn_s_barrier();                        // all waves' stripes landed
    short8 af[4], bf[4];
#pragma unroll
    for (int i2 = 0; i2 < 4; ++i2) af[i2] = *(const short8*)&As[cur][lds_ix(wm + i2 * 16 + lr, lk)];
#pragma unroll
    for (int j2 = 0; j2 < 4; ++j2) bf[j2] = *(const short8*)&Bs[cur][lds_ix(wn + j2 * 16 + lr, lk)];
#pragma unroll
    for (int i2 = 0; i2 < 4; ++i2)
#pragma unroll
      for (int j2 = 0; j2 < 4; ++j2)
        acc[i2][j2] = __builtin_amdgcn_mfma_f32_16x16x32_bf16(af[i2], bf[j2], acc[i2][j2], 0, 0, 0);
    __builtin_amdgcn_s_barrier();                        // all reads of buf[cur] consumed
    if (kt + 64 < K) {                                   // refill freed buffer, tile kt+64
      GLOAD_LDS16(Ag + kt + 64, &As[cur][woff]);
      GLOAD_LDS16(Ag + kt + 64 + (size_t)16 * K, &As[cur][woff + 16 * 32]);
      GLOAD_LDS16(Bg + kt + 64, &Bs[cur][woff]);
      GLOAD_LDS16(Bg + kt + 64 + (size_t)16 * K, &Bs[cur][woff + 16 * 32]);
    }
    cur ^= 1;
  }
  // ======== fused epilogue (unchanged from round 12) ========
  int col_lo = wn + lr;                      // + j2*16
  for (int chunk = 0; chunk < 2; ++chunk) {
    __syncthreads();                         // ob WAR vs previous chunk reads
#pragma unroll
    for (int j2c = 0; j2c < 2; ++j2c) {
      int j2 = chunk * 2 + j2c;
      int col = col_lo + j2 * 16;            // 0..127
      int nglob = bn * 128 + col;
      int q = nglob >> 1;
      float bias = 0.f;
      if (q < P_) bias = pb[(nglob & 1) ? (P_ + q) : q];
      int qloc = col >> 1;
      int s = (qloc & 15) | ((qloc >> 5) << 4);   // chunk-local slot 0..31
#pragma unroll
      for (int i2 = 0; i2 < 4; ++i2) {
        int row = wm + i2 * 16 + lk * 4;
        float res[4];
#pragma unroll
        for (int rgi = 0; rgi < 4; ++rgi) {
          float val = acc[i2][j2][rgi] + bias;
          float other = __shfl_xor(val, 1);
          float4 m = mv[bm * 128 + row + rgi];
          res[rgi] = val * (1.0f / (1.0f + __expf(-other))) * m.y + m.x;
        }
        if (!(lane & 1)) {
          *(float4*)&ob[s * 132 + row] = make_float4(res[0], res[1], res[2], res[3]);
        }
      }
    }
    __syncthreads();
    int c = tid & 63, sl4 = tid >> 6;
    for (int rd = 0; rd < 16; ++rd) {
      int slice = rd * 4 + sl4;
      int s = slice >> 1, bb = slice & 1;
      int qloc = (s & 15) + chunk * 16 + ((s >> 4) << 5);
      int qglob = bn * 64 + qloc;
      if (qglob < P_) {
        int bg = bm * 2 + bb;
        out[((size_t)bg * P_ + qglob) * 64 + c] = ob[s * 132 + bb * 64 + c];
      }
    }
  }
}

extern "C" void kernel_launch(void* const* d_in, const int* in_sizes, int n_in,
                              void* d_out, int out_size, void* d_ws, size_t ws_size,
                              hipStream_t stream) {
  const float* u   = (const float*)d_in[0];
  const float* Wn  = (const float*)d_in[4];
  const float* Dv  = (const float*)d_in[5];
  const float* lv  = (const float*)d_in[6];
  const float* Cp  = (const float*)d_in[7];
  const float* ldt = (const float*)d_in[8];
  const float* lAr = (const float*)d_in[9];
  const float* Aim = (const float*)d_in[10];
  const float* pw  = (const float*)d_in[11];
  const float* pb  = (const float*)d_in[12];
  float* out = (float*)d_out;
  char* ws = (char*)d_ws;

  // workspace layout (bytes)
  float2* tw = (float2*)(ws + 0);                  // 2 KB
  float4* mv = (float4*)(ws + (64 << 10));         // 128 KB  -> ends 192 KB
  float2* G  = (float2*)(ws + (1 << 20));          // 2 MB    -> ends 3 MB
  float2* kz = (float2*)(ws + (3 << 20));          // 1 MB    -> ends 4 MB
  u16*    Wb = (u16*)   (ws + (4 << 20));          // 6 MB    -> ends 10 MB
  float*  ps = (float*) (ws + (10 << 20));         // 512 KB
  float*  pq = (float*) (ws + (10 << 20) + (512 << 10)); // 512 KB -> ends 11 MB
  u16*    yT = (u16*)   (ws + (16 << 20));         // 32 MB   -> ends 48 MB
  u32*    zu = (u32*)   (ws + ((size_t)48 << 20)); // 64 MB   -> ends 112 MB

  k_prep<<<PREP_NB, 256, 0, stream>>>(pw, Wb, u, ps, pq, Cp, ldt, lAr, Aim, kz, tw);
  k_packfftk<<<PF_NB, 256, 0, stream>>>(u, Wn, lv, ps, pq, zu, kz, tw, G, mv);
  k_fftmain<<<NROW, 256, 0, stream>>>(zu, tw, G, Dv, yT);
  k_gemm<<<64 * (NPAD / 128), 256, 0, stream>>>(yT, Wb, pb, mv, out);
}

// Round 14
// 315.231 us; speedup vs baseline: 1.0405x; 1.0405x over previous
//
#include <hip/hip_runtime.h>
#include <math.h>

typedef unsigned short u16;
typedef unsigned int u32;
typedef __attribute__((ext_vector_type(8))) short short8;
typedef __attribute__((ext_vector_type(4))) float f32x4;

// Problem constants
#define B_   128
#define L_   2048
#define C_   64
#define P_   720
#define P2_  1440
#define NPAD 1536     // proj cols padded to multiple of 128 (interleaved a/g)
#define NFFT 4096
#define NROW (B_*C_)  // 8192
#define TCHUNK 16     // time chunks for stats phase 1

// prep-kernel block ranges (longest blocks first)
#define PREP_SSMK   512
#define PREP_STATS1 2048
#define PREP_NB     (PREP_SSMK + PREP_STATS1 + 1 + (NPAD * L_) / 256)
// packfftk ranges
#define PF_PACK  4096
#define PF_FFTK  64
#define PF_NB    (PF_PACK + PF_FFTK + 32)

// global -> LDS direct staging, 16 B per lane; LDS dest = uniform base + lane*16
#define GLOAD_LDS16(g, l) __builtin_amdgcn_global_load_lds( \
    (const __attribute__((address_space(1))) unsigned int*)(g), \
    (__attribute__((address_space(3))) unsigned int*)(l), 16, 0, 0)

__device__ __forceinline__ u16 f2bf(float f) {
  union { float f; unsigned u; } x; x.f = f;
  unsigned r = x.u + 0x7fffu + ((x.u >> 16) & 1u);
  return (u16)(r >> 16);
}
__device__ __forceinline__ float bf2f_lo(u32 v) {
  union { unsigned u; float f; } x; x.u = v << 16; return x.f;
}
__device__ __forceinline__ float bf2f_hi(u32 v) {
  union { unsigned u; float f; } x; x.u = v & 0xffff0000u; return x.f;
}

__device__ __forceinline__ float2 cmul(float2 a, float2 b) {
  return make_float2(a.x * b.x - a.y * b.y, a.x * b.y + a.y * b.x);
}
__device__ __forceinline__ float2 cadd(float2 a, float2 b) { return make_float2(a.x + b.x, a.y + b.y); }
__device__ __forceinline__ float2 csub(float2 a, float2 b) { return make_float2(a.x - b.x, a.y - b.y); }

#define CSWAP(i, j) { float2 tt = a[i]; a[i] = a[j]; a[j] = tt; }

// ===================== 16-point DFT in registers =====================
template<bool INV, bool HZ>
__device__ __forceinline__ void dft16(float2 a[16]) {
  const float S  = INV ? 1.f : -1.f;
  const float c1 = 0.9238795325112867f, s1 = 0.3826834323650898f, q2 = 0.7071067811865476f;
  const float2 W1 = make_float2( c1, S * s1), W2 = make_float2( q2, S * q2), W3 = make_float2( s1, S * c1);
  const float2 W5 = make_float2(-s1, S * c1), W6 = make_float2(-q2, S * q2), W7 = make_float2(-c1, S * s1);
  if (HZ) {
    a[8]  = a[0];
    a[9]  = cmul(a[1], W1);
    a[10] = cmul(a[2], W2);
    a[11] = cmul(a[3], W3);
    a[12] = make_float2(-S * a[4].y, S * a[4].x);
    a[13] = cmul(a[5], W5);
    a[14] = cmul(a[6], W6);
    a[15] = cmul(a[7], W7);
  } else {
    float2 t;
    t = csub(a[0], a[8]);  a[0] = cadd(a[0], a[8]);  a[8]  = t;
    t = csub(a[1], a[9]);  a[1] = cadd(a[1], a[9]);  a[9]  = cmul(t, W1);
    t = csub(a[2], a[10]); a[2] = cadd(a[2], a[10]); a[10] = cmul(t, W2);
    t = csub(a[3], a[11]); a[3] = cadd(a[3], a[11]); a[11] = cmul(t, W3);
    t = csub(a[4], a[12]); a[4] = cadd(a[4], a[12]); a[12] = make_float2(-S * t.y, S * t.x);
    t = csub(a[5], a[13]); a[5] = cadd(a[5], a[13]); a[13] = cmul(t, W5);
    t = csub(a[6], a[14]); a[6] = cadd(a[6], a[14]); a[14] = cmul(t, W6);
    t = csub(a[7], a[15]); a[7] = cadd(a[7], a[15]); a[15] = cmul(t, W7);
  }
#pragma unroll
  for (int h = 0; h < 16; h += 8) {
    float2 t;
    t = csub(a[h+0], a[h+4]); a[h+0] = cadd(a[h+0], a[h+4]); a[h+4] = t;
    t = csub(a[h+1], a[h+5]); a[h+1] = cadd(a[h+1], a[h+5]); a[h+5] = cmul(t, W2);
    t = csub(a[h+2], a[h+6]); a[h+2] = cadd(a[h+2], a[h+6]); a[h+6] = make_float2(-S * t.y, S * t.x);
    t = csub(a[h+3], a[h+7]); a[h+3] = cadd(a[h+3], a[h+7]); a[h+7] = cmul(t, W6);
  }
#pragma unroll
  for (int q = 0; q < 16; q += 4) {
    float2 t;
    t = csub(a[q+0], a[q+2]); a[q+0] = cadd(a[q+0], a[q+2]); a[q+2] = t;
    t = csub(a[q+1], a[q+3]); a[q+1] = cadd(a[q+1], a[q+3]); a[q+3] = make_float2(-S * t.y, S * t.x);
  }
#pragma unroll
  for (int p = 0; p < 16; p += 2) {
    float2 t = csub(a[p], a[p+1]); a[p] = cadd(a[p], a[p+1]); a[p+1] = t;
  }
  CSWAP(1, 8); CSWAP(2, 4); CSWAP(3, 12); CSWAP(5, 10); CSWAP(7, 14); CSWAP(11, 13);
}

// twiddle apply: a[k] *= w1^k. Powers via binary tree (depth 4) -> independent applies (ILP).
__device__ __forceinline__ void twchain(float2 a[16], float2 w1) {
  float2 w2 = cmul(w1, w1);
  float2 w3 = cmul(w2, w1);
  float2 w4 = cmul(w2, w2);
  float2 w5 = cmul(w3, w2);
  float2 w6 = cmul(w3, w3);
  float2 w7 = cmul(w4, w3);
  float2 w8 = cmul(w4, w4);
  float2 w9 = cmul(w5, w4);
  float2 w10 = cmul(w5, w5);
  float2 w11 = cmul(w6, w5);
  float2 w12 = cmul(w6, w6);
  float2 w13 = cmul(w7, w6);
  float2 w14 = cmul(w7, w7);
  float2 w15 = cmul(w8, w7);
  a[1]  = cmul(a[1],  w1);  a[2]  = cmul(a[2],  w2);  a[3]  = cmul(a[3],  w3);
  a[4]  = cmul(a[4],  w4);  a[5]  = cmul(a[5],  w5);  a[6]  = cmul(a[6],  w6);
  a[7]  = cmul(a[7],  w7);  a[8]  = cmul(a[8],  w8);  a[9]  = cmul(a[9],  w9);
  a[10] = cmul(a[10], w10); a[11] = cmul(a[11], w11); a[12] = cmul(a[12], w12);
  a[13] = cmul(a[13], w13); a[14] = cmul(a[14], w14); a[15] = cmul(a[15], w15);
}

// ===================== swizzled LDS transposes (FFT) =====================
__device__ __forceinline__ void lds_wA(float2* X, const float2 r[16], int tid) {
  int base = (tid & 15) * 16 + ((tid >> 4) ^ ((tid & 7) << 1));
#pragma unroll
  for (int i = 0; i < 16; ++i) X[base + i * 256] = r[i];
}
__device__ __forceinline__ void lds_wB(float2* X, const float2 r[16], int tid) {
#pragma unroll
  for (int i = 0; i < 16; ++i)
    X[((tid & 0xF0) + i) * 16 + ((tid & 15) ^ ((i & 7) << 1))] = r[i];
}
__device__ __forceinline__ void lds_rd(const float2* X, float2 r[16], int tid) {
  const float4* X4 = (const float4*)X;
#pragma unroll
  for (int p = 0; p < 8; ++p) {
    float4 v = X4[tid * 8 + (p ^ (tid & 7))];
    r[2 * p]     = make_float2(v.x, v.y);
    r[2 * p + 1] = make_float2(v.z, v.w);
  }
}

__device__ __forceinline__ void fft_fwd_hz(float2 r[16], float2* X, int tid, const float2* twg) {
  dft16<false, true>(r);
  twchain(r, twg[tid]);
  lds_wA(X, r, tid);
  __syncthreads();
  lds_rd(X, r, tid);
  dft16<false, false>(r);
  twchain(r, twg[(tid & 15) << 4]);
  __syncthreads();
  lds_wB(X, r, tid);
  __syncthreads();
  lds_rd(X, r, tid);
  dft16<false, false>(r);
}

__device__ __forceinline__ void fft_inv(float2 r[16], float2* X, int tid, const float2* twg) {
  dft16<true, false>(r);
  __syncthreads();
  lds_wB(X, r, tid);
  __syncthreads();
  lds_rd(X, r, tid);
  float2 wb = twg[(tid & 15) << 4];
  twchain(r, make_float2(wb.x, -wb.y));
  dft16<true, false>(r);
  __syncthreads();
  lds_wA(X, r, tid);
  __syncthreads();
  lds_rd(X, r, tid);
  float2 wa = twg[tid];
  twchain(r, make_float2(wa.x, -wa.y));
  dft16<true, false>(r);
}

// ===================== fused prep: ssmk + stats1 + twfill + wconv =====================
__global__ __launch_bounds__(256) void k_prep(const float* __restrict__ pw, u16* __restrict__ wb,
                                              const float* __restrict__ u, float* __restrict__ ps,
                                              float* __restrict__ pq,
                                              const float* __restrict__ Cp, const float* __restrict__ ldt,
                                              const float* __restrict__ lAr, const float* __restrict__ Aim,
                                              float2* __restrict__ kz, float2* __restrict__ tw) {
  __shared__ float4 sb[16][16], qb[16][16];
  int blk = blockIdx.x, tid = threadIdx.x;
  if (blk < PREP_SSMK) {
    // ---- ssmk (longest blocks first) ----
    int gid = blk * 256 + tid;   // 64*2048
    int h = gid & 2047;
    int j = gid >> 11;
    float dt = expf(ldt[h]);
    float accx = 0.f;
    float Ar0 = 0.f;
    for (int n = 0; n < 64; ++n) {
      float Ar = -expf(lAr[h * 64 + n]);
      float Ai = Aim[h * 64 + n];
      if (n == 0) Ar0 = Ar;
      float dAr = Ar * dt, dAi = Ai * dt;
      float er = expf(dAr);
      float s1, c1; sincosf(dAi, &s1, &c1);
      float emr = er * c1 - 1.0f, emi = er * s1;
      float inv = 1.0f / (Ar * Ar + Ai * Ai);
      float qr = (emr * Ar + emi * Ai) * inv;
      float qi = (emi * Ar - emr * Ai) * inv;
      float cr = Cp[(size_t)(h * 64 + n) * 2];
      float ci = Cp[(size_t)(h * 64 + n) * 2 + 1];
      float ccr = cr * qr - ci * qi;
      float cci = cr * qi + ci * qr;
      float ej = expf(dAr * (float)j);
      float sj, cj; sincosf(dAi * (float)j, &sj, &cj);
      accx += ccr * (ej * cj) - cci * (ej * sj);
    }
    float K = 2.0f * accx;
    float K2 = 2.0f * K * (Ar0 * (float)j * dt);
    kz[(size_t)j * L_ + h] = make_float2(K2, -K);        // pack K2 - i*K
  } else if (blk < PREP_SSMK + PREP_STATS1) {
    // ---- stats1 ----
    int blk2 = blk - PREP_SSMK;          // b*TCHUNK + q
    int b = blk2 >> 4, q = blk2 & 15;
    int c4 = tid & 15, g = tid >> 4;     // 16 groups x 8 t-steps
    const float4* u4 = (const float4*)(u + ((size_t)b * L_ + q * 128) * C_);
    float4 s = make_float4(0.f, 0.f, 0.f, 0.f), sq = s;
#pragma unroll
    for (int i = 0; i < 8; ++i) {
      float4 v = u4[(size_t)(g + 16 * i) * 16 + c4];
      s.x += v.x; s.y += v.y; s.z += v.z; s.w += v.w;
      sq.x += v.x * v.x; sq.y += v.y * v.y; sq.z += v.z * v.z; sq.w += v.w * v.w;
    }
    sb[g][c4] = s; qb[g][c4] = sq;
    __syncthreads();
    if (g == 0) {
      float4 S = sb[0][c4], Q = qb[0][c4];
#pragma unroll
      for (int k = 1; k < 16; ++k) {
        float4 a = sb[k][c4], d = qb[k][c4];
        S.x += a.x; S.y += a.y; S.z += a.z; S.w += a.w;
        Q.x += d.x; Q.y += d.y; Q.z += d.z; Q.w += d.w;
      }
      ((float4*)ps)[blk2 * 16 + c4] = S;
      ((float4*)pq)[blk2 * 16 + c4] = Q;
    }
  } else if (blk == PREP_SSMK + PREP_STATS1) {
    // ---- twfill ----
    int k = tid;
    double ang = -2.0 * 3.14159265358979323846 * (double)k / 4096.0;
    tw[k] = make_float2((float)cos(ang), (float)sin(ang));
  } else {
    // ---- wconv: interleaved (a,g) proj rows -> bf16 ----
    size_t idx = (size_t)(blk - (PREP_SSMK + PREP_STATS1 + 1)) * 256 + tid;
    int n = (int)(idx >> 11);
    int k = (int)(idx & 2047);
    int q = n >> 1;
    float v = 0.f;
    if (q < P_) {
      int p = (n & 1) ? (P_ + q) : q;
      v = pw[(size_t)p * L_ + k];
    }
    wb[idx] = f2bf(v);
  }
}

// ===================== fused: packT (inline mv) + fftk + stats2(for gemm) =====================
__global__ __launch_bounds__(256) void k_packfftk(const float* __restrict__ u, const float* __restrict__ Wn,
                                                  const float* __restrict__ lv,
                                                  const float* __restrict__ ps, const float* __restrict__ pq,
                                                  u32* __restrict__ zu,
                                                  const float2* __restrict__ kz, const float2* __restrict__ twg,
                                                  float2* __restrict__ G, float4* __restrict__ mv) {
  __shared__ __align__(16) char smem[33280];
  int blk = blockIdx.x, tid = threadIdx.x;
  if (blk < PF_PACK) {
    // ---- packT with inline per-block mv recompute (bit-identical to stats2) ----
    int b = blk >> 5;
    int t0 = (blk & 31) << 6;
    float4* mvs = (float4*)smem;           // transient, first 1 KB
    if (tid < 64) {
      float S = 0.f, Q = 0.f;
#pragma unroll
      for (int q = 0; q < 16; ++q) {
        S += ps[(size_t)(b * 16 + q) * 64 + tid];
        Q += pq[(size_t)(b * 16 + q) * 64 + tid];
      }
      float mean = S * (1.0f / 2048.0f);
      float var = (Q - S * S * (1.0f / 2048.0f)) * (1.0f / 2047.0f) + 1e-5f;
      float sv = sqrtf(var);
      mvs[tid] = make_float4(mean, sv, 1.0f / sv, 0.0f);
    }
    __syncthreads();
    int c = tid & 63, r = tid >> 6;
    float4 m = mvs[c];
    float stdn = sqrtf(__expf(lv[0]));
    __syncthreads();                       // mvs reads done before tile overwrites
    float2 (*tile)[65] = (float2(*)[65])smem;
#pragma unroll
    for (int i = 0; i < 16; ++i) {
      int t = t0 + i * 4 + r;
      size_t idx = ((size_t)b * L_ + t) * C_ + c;
      float uu = (u[idx] - m.x) * m.z;
      float ww = Wn[idx] * stdn;
      tile[i * 4 + r][c] = make_float2(uu, ww);
    }
    __syncthreads();
    int t = tid & 63, cb = tid >> 6;
#pragma unroll
    for (int i = 0; i < 16; ++i) {
      int c2 = i * 4 + cb;
      float2 v = tile[t][c2];
      zu[((size_t)(b * C_ + c2)) * L_ + t0 + t] = ((u32)f2bf(v.y) << 16) | (u32)f2bf(v.x);
    }
  } else if (blk < PF_PACK + PF_FFTK) {
    // ---- fftk: G[j] = FFT(K2 - iK)/4096 ----
    float2* X = (float2*)smem;
    int j = blk - PF_PACK;
    float2 r[16];
#pragma unroll
    for (int n2 = 0; n2 < 8; ++n2) r[n2] = kz[(size_t)j * L_ + n2 * 256 + tid];
    fft_fwd_hz(r, X, tid, twg);
    const float sc = 1.0f / 4096.0f;
#pragma unroll
    for (int k0 = 0; k0 < 16; ++k0)
      G[(size_t)j * NFFT + k0 * 256 + tid] = make_float2(r[k0].x * sc, r[k0].y * sc);
  } else {
    // ---- stats2: mv for the gemm epilogue (consumed 2 kernels later) ----
    int gid = (blk - (PF_PACK + PF_FFTK)) * 256 + tid;   // 8192
    int b = gid >> 6, c = gid & 63;
    float S = 0.f, Q = 0.f;
#pragma unroll
    for (int q = 0; q < 16; ++q) {
      S += ps[(size_t)(b * 16 + q) * 64 + c];
      Q += pq[(size_t)(b * 16 + q) * 64 + c];
    }
    float mean = S * (1.0f / 2048.0f);
    float var = (Q - S * S * (1.0f / 2048.0f)) * (1.0f / 2047.0f) + 1e-5f;
    float sv = sqrtf(var);
    mv[gid] = make_float4(mean, sv, 1.0f / sv, 0.0f);
  }
}

// ===================== main conv per row: y = Re(IFFT(FFT(z) .* G)) + un*D =====================
__global__ __launch_bounds__(256) void k_fftmain(const u32* __restrict__ zu, const float2* __restrict__ twg,
                                                 const float2* __restrict__ G, const float* __restrict__ Dv,
                                                 u16* __restrict__ yT) {
  __shared__ float2 X[NFFT];
  int row = blockIdx.x;           // b*64 + j
  int j = row & 63;
  int tid = threadIdx.x;
  float2 r[16];
  float usav[8];
#pragma unroll
  for (int n2 = 0; n2 < 8; ++n2) {
    u32 v = zu[(size_t)row * L_ + n2 * 256 + tid];
    float uu = bf2f_lo(v), ww = bf2f_hi(v);
    r[n2] = make_float2(uu, ww);
    usav[n2] = uu;
  }
  fft_fwd_hz(r, X, tid, twg);
  const float2* Gj = G + (size_t)j * NFFT;
#pragma unroll
  for (int k0 = 0; k0 < 16; ++k0) r[k0] = cmul(r[k0], Gj[k0 * 256 + tid]);
  fft_inv(r, X, tid, twg);
#pragma unroll
  for (int n2 = 8; n2 < 16; ++n2) {
    int t = (n2 - 8) * 256 + tid;
    float yv = r[n2].x + usav[n2 - 8] * Dv[t];
    yT[(size_t)row * L_ + t] = f2bf(yv);
  }
}

// ===================== bf16 MFMA GEMM — 2-deep pipeline, 32 KB LDS (ob aliased), bm-per-XCD map =====
// C[M=8192][N=1536] = yT[M][K=2048] * Wb[N][K]^T, Wb cols interleaved (a,g) pairs.
// LDS: As/Bs dbuf 32 KB total; epilogue buffer ob ALIASES this region (K-loop reads all
// consumed before the epilogue's first barrier) -> 5 blocks/CU (was 3 at 49.6 KB).
// XCD map: XCD x owns bm in [8x, 8x+8) for all bn -> each A-stripe lives in exactly one L2.
__device__ __forceinline__ int lds_ix(int row, int slot) {
  return row * 32 + ((slot ^ ((row >> 1) & 3)) << 3);   // u16 units
}

__global__ __launch_bounds__(256) void k_gemm(const u16* __restrict__ A, const u16* __restrict__ B,
                                              const float* __restrict__ pb, const float4* __restrict__ mv,
                                              float* __restrict__ out) {
  __shared__ __align__(16) char gsm[32768];
  u16 (*As)[128 * 32] = (u16(*)[128 * 32])gsm;            // 2 x 8 KB
  u16 (*Bs)[128 * 32] = (u16(*)[128 * 32])(gsm + 16384);  // 2 x 8 KB
  float* ob = (float*)gsm;                                 // 16.9 KB, aliases As/Bs (epilogue only)
  const int K = L_;
  int tid = threadIdx.x;
  // bm-contiguous per-XCD map: x = bid&7 -> XCD (dispatch round-robin), bm = x*8 + ((bid>>3)&7),
  // bn = bid>>6.  Bijective over 768 = 8 x 8 x 12.
  int bid = blockIdx.x;
  int bm = (bid & 7) * 8 + ((bid >> 3) & 7);
  int bn = bid >> 6;
  int wave = tid >> 6, lane = tid & 63;
  int wm = (wave >> 1) << 6, wn = (wave & 1) << 6;
  int lr = lane & 15, lk = lane >> 4;
  // staging: wave w stages rows [w*32, w*32+32), 2 issues of 16 rows each.
  // LDS dest LINEAR; read side uses lds_ix swizzle -> global SOURCE col pre-swizzled (rule #21).
  // sw(row+16)==sw(row) since ((r+16)>>1)&3 == (r>>1)&3.
  int srow = wave * 32 + (lane >> 2);
  int sslot = lane & 3;
  int scol = (sslot ^ ((srow >> 1) & 3)) << 3;
  const u16* Ag = A + (size_t)(bm * 128 + srow) * K + scol;
  const u16* Bg = B + (size_t)(bn * 128 + srow) * K + scol;
  int woff = wave * 32 * 32;
  f32x4 acc[4][4] = {};
  // prologue: 2 tiles in flight (8 gload_lds)
  GLOAD_LDS16(Ag, &As[0][woff]);
  GLOAD_LDS16(Ag + (size_t)16 * K, &As[0][woff + 16 * 32]);
  GLOAD_LDS16(Bg, &Bs[0][woff]);
  GLOAD_LDS16(Bg + (size_t)16 * K, &Bs[0][woff + 16 * 32]);
  GLOAD_LDS16(Ag + 32, &As[1][woff]);
  GLOAD_LDS16(Ag + 32 + (size_t)16 * K, &As[1][woff + 16 * 32]);
  GLOAD_LDS16(Bg + 32, &Bs[1][woff]);
  GLOAD_LDS16(Bg + 32 + (size_t)16 * K, &Bs[1][woff + 16 * 32]);
  int cur = 0;
  for (int kt = 0; kt < K; kt += 32) {
    if (kt + 32 < K) {
      asm volatile("s_waitcnt vmcnt(4)" ::: "memory");   // oldest tile landed (per-wave)
    } else {
      asm volatile("s_waitcnt vmcnt(0)" ::: "memory");   // last tile: drain
    }
    __builtin_amdgcn_s_barrier();                        // all waves' stripes landed
    short8 af[4], bf[4];
#pragma unroll
    for (int i2 = 0; i2 < 4; ++i2) af[i2] = *(const short8*)&As[cur][lds_ix(wm + i2 * 16 + lr, lk)];
#pragma unroll
    for (int j2 = 0; j2 < 4; ++j2) bf[j2] = *(const short8*)&Bs[cur][lds_ix(wn + j2 * 16 + lr, lk)];
#pragma unroll
    for (int i2 = 0; i2 < 4; ++i2)
#pragma unroll
      for (int j2 = 0; j2 < 4; ++j2)
        acc[i2][j2] = __builtin_amdgcn_mfma_f32_16x16x32_bf16(af[i2], bf[j2], acc[i2][j2], 0, 0, 0);
    __builtin_amdgcn_s_barrier();                        // all reads of buf[cur] consumed
    if (kt + 64 < K) {                                   // refill freed buffer, tile kt+64
      GLOAD_LDS16(Ag + kt + 64, &As[cur][woff]);
      GLOAD_LDS16(Ag + kt + 64 + (size_t)16 * K, &As[cur][woff + 16 * 32]);
      GLOAD_LDS16(Bg + kt + 64, &Bs[cur][woff]);
      GLOAD_LDS16(Bg + kt + 64 + (size_t)16 * K, &Bs[cur][woff + 16 * 32]);
    }
    cur ^= 1;
  }
  // ======== fused epilogue (ob aliases As/Bs; barrier below makes the WAR safe) ========
  int col_lo = wn + lr;                      // + j2*16
  for (int chunk = 0; chunk < 2; ++chunk) {
    __syncthreads();                         // K-loop LDS reads / prev chunk reads complete
#pragma unroll
    for (int j2c = 0; j2c < 2; ++j2c) {
      int j2 = chunk * 2 + j2c;
      int col = col_lo + j2 * 16;            // 0..127
      int nglob = bn * 128 + col;
      int q = nglob >> 1;
      float bias = 0.f;
      if (q < P_) bias = pb[(nglob & 1) ? (P_ + q) : q];
      int qloc = col >> 1;
      int s = (qloc & 15) | ((qloc >> 5) << 4);   // chunk-local slot 0..31
#pragma unroll
      for (int i2 = 0; i2 < 4; ++i2) {
        int row = wm + i2 * 16 + lk * 4;
        float res[4];
#pragma unroll
        for (int rgi = 0; rgi < 4; ++rgi) {
          float val = acc[i2][j2][rgi] + bias;
          float other = __shfl_xor(val, 1);
          float4 m = mv[bm * 128 + row + rgi];
          res[rgi] = val * (1.0f / (1.0f + __expf(-other))) * m.y + m.x;
        }
        if (!(lane & 1)) {
          *(float4*)&ob[s * 132 + row] = make_float4(res[0], res[1], res[2], res[3]);
        }
      }
    }
    __syncthreads();
    int c = tid & 63, sl4 = tid >> 6;
    for (int rd = 0; rd < 16; ++rd) {
      int slice = rd * 4 + sl4;
      int s = slice >> 1, bb = slice & 1;
      int qloc = (s & 15) + chunk * 16 + ((s >> 4) << 5);
      int qglob = bn * 64 + qloc;
      if (qglob < P_) {
        int bg = bm * 2 + bb;
        out[((size_t)bg * P_ + qglob) * 64 + c] = ob[s * 132 + bb * 64 + c];
      }
    }
  }
}

extern "C" void kernel_launch(void* const* d_in, const int* in_sizes, int n_in,
                              void* d_out, int out_size, void* d_ws, size_t ws_size,
                              hipStream_t stream) {
  const float* u   = (const float*)d_in[0];
  const float* Wn  = (const float*)d_in[4];
  const float* Dv  = (const float*)d_in[5];
  const float* lv  = (const float*)d_in[6];
  const float* Cp  = (const float*)d_in[7];
  const float* ldt = (const float*)d_in[8];
  const float* lAr = (const float*)d_in[9];
  const float* Aim = (const float*)d_in[10];
  const float* pw  = (const float*)d_in[11];
  const float* pb  = (const float*)d_in[12];
  float* out = (float*)d_out;
  char* ws = (char*)d_ws;

  // workspace layout (bytes)
  float2* tw = (float2*)(ws + 0);                  // 2 KB
  float4* mv = (float4*)(ws + (64 << 10));         // 128 KB  -> ends 192 KB
  float2* G  = (float2*)(ws + (1 << 20));          // 2 MB    -> ends 3 MB
  float2* kz = (float2*)(ws + (3 << 20));          // 1 MB    -> ends 4 MB
  u16*    Wb = (u16*)   (ws + (4 << 20));          // 6 MB    -> ends 10 MB
  float*  ps = (float*) (ws + (10 << 20));         // 512 KB
  float*  pq = (float*) (ws + (10 << 20) + (512 << 10)); // 512 KB -> ends 11 MB
  u16*    yT = (u16*)   (ws + (16 << 20));         // 32 MB   -> ends 48 MB
  u32*    zu = (u32*)   (ws + ((size_t)48 << 20)); // 64 MB   -> ends 112 MB

  k_prep<<<PREP_NB, 256, 0, stream>>>(pw, Wb, u, ps, pq, Cp, ldt, lAr, Aim, kz, tw);
  k_packfftk<<<PF_NB, 256, 0, stream>>>(u, Wn, lv, ps, pq, zu, kz, tw, G, mv);
  k_fftmain<<<NROW, 256, 0, stream>>>(zu, tw, G, Dv, yT);
  k_gemm<<<64 * (NPAD / 128), 256, 0, stream>>>(yT, Wb, pb, mv, out);
}

// Round 15
// 310.016 us; speedup vs baseline: 1.0580x; 1.0168x over previous
//
#include <hip/hip_runtime.h>
#include <math.h>

typedef unsigned short u16;
typedef unsigned int u32;
typedef __attribute__((ext_vector_type(8))) short short8;
typedef __attribute__((ext_vector_type(4))) float f32x4;

// Problem constants
#define B_   128
#define L_   2048
#define C_   64
#define P_   720
#define P2_  1440
#define NPAD 1536     // proj cols padded to multiple of 128 (interleaved a/g)
#define NFFT 4096
#define NROW (B_*C_)  // 8192
#define TCHUNK 16     // time chunks for stats phase 1

// prep-kernel block ranges (longest blocks first)
#define PREP_SSMK   512
#define PREP_STATS1 2048
#define PREP_NB     (PREP_SSMK + PREP_STATS1 + 1 + (NPAD * L_) / 256)
// packfftk ranges
#define PF_PACK  4096
#define PF_FFTK  64
#define PF_NB    (PF_PACK + PF_FFTK + 32)

// global -> LDS direct staging, 16 B per lane; LDS dest = uniform base + lane*16
#define GLOAD_LDS16(g, l) __builtin_amdgcn_global_load_lds( \
    (const __attribute__((address_space(1))) unsigned int*)(g), \
    (__attribute__((address_space(3))) unsigned int*)(l), 16, 0, 0)

__device__ __forceinline__ u16 f2bf(float f) {
  union { float f; unsigned u; } x; x.f = f;
  unsigned r = x.u + 0x7fffu + ((x.u >> 16) & 1u);
  return (u16)(r >> 16);
}
__device__ __forceinline__ float bf2f_lo(u32 v) {
  union { unsigned u; float f; } x; x.u = v << 16; return x.f;
}
__device__ __forceinline__ float bf2f_hi(u32 v) {
  union { unsigned u; float f; } x; x.u = v & 0xffff0000u; return x.f;
}

__device__ __forceinline__ float2 cmul(float2 a, float2 b) {
  return make_float2(a.x * b.x - a.y * b.y, a.x * b.y + a.y * b.x);
}
__device__ __forceinline__ float2 cadd(float2 a, float2 b) { return make_float2(a.x + b.x, a.y + b.y); }
__device__ __forceinline__ float2 csub(float2 a, float2 b) { return make_float2(a.x - b.x, a.y - b.y); }

#define CSWAP(i, j) { float2 tt = a[i]; a[i] = a[j]; a[j] = tt; }

// ===================== 16-point DFT in registers =====================
template<bool INV, bool HZ>
__device__ __forceinline__ void dft16(float2 a[16]) {
  const float S  = INV ? 1.f : -1.f;
  const float c1 = 0.9238795325112867f, s1 = 0.3826834323650898f, q2 = 0.7071067811865476f;
  const float2 W1 = make_float2( c1, S * s1), W2 = make_float2( q2, S * q2), W3 = make_float2( s1, S * c1);
  const float2 W5 = make_float2(-s1, S * c1), W6 = make_float2(-q2, S * q2), W7 = make_float2(-c1, S * s1);
  if (HZ) {
    a[8]  = a[0];
    a[9]  = cmul(a[1], W1);
    a[10] = cmul(a[2], W2);
    a[11] = cmul(a[3], W3);
    a[12] = make_float2(-S * a[4].y, S * a[4].x);
    a[13] = cmul(a[5], W5);
    a[14] = cmul(a[6], W6);
    a[15] = cmul(a[7], W7);
  } else {
    float2 t;
    t = csub(a[0], a[8]);  a[0] = cadd(a[0], a[8]);  a[8]  = t;
    t = csub(a[1], a[9]);  a[1] = cadd(a[1], a[9]);  a[9]  = cmul(t, W1);
    t = csub(a[2], a[10]); a[2] = cadd(a[2], a[10]); a[10] = cmul(t, W2);
    t = csub(a[3], a[11]); a[3] = cadd(a[3], a[11]); a[11] = cmul(t, W3);
    t = csub(a[4], a[12]); a[4] = cadd(a[4], a[12]); a[12] = make_float2(-S * t.y, S * t.x);
    t = csub(a[5], a[13]); a[5] = cadd(a[5], a[13]); a[13] = cmul(t, W5);
    t = csub(a[6], a[14]); a[6] = cadd(a[6], a[14]); a[14] = cmul(t, W6);
    t = csub(a[7], a[15]); a[7] = cadd(a[7], a[15]); a[15] = cmul(t, W7);
  }
#pragma unroll
  for (int h = 0; h < 16; h += 8) {
    float2 t;
    t = csub(a[h+0], a[h+4]); a[h+0] = cadd(a[h+0], a[h+4]); a[h+4] = t;
    t = csub(a[h+1], a[h+5]); a[h+1] = cadd(a[h+1], a[h+5]); a[h+5] = cmul(t, W2);
    t = csub(a[h+2], a[h+6]); a[h+2] = cadd(a[h+2], a[h+6]); a[h+6] = make_float2(-S * t.y, S * t.x);
    t = csub(a[h+3], a[h+7]); a[h+3] = cadd(a[h+3], a[h+7]); a[h+7] = cmul(t, W6);
  }
#pragma unroll
  for (int q = 0; q < 16; q += 4) {
    float2 t;
    t = csub(a[q+0], a[q+2]); a[q+0] = cadd(a[q+0], a[q+2]); a[q+2] = t;
    t = csub(a[q+1], a[q+3]); a[q+1] = cadd(a[q+1], a[q+3]); a[q+3] = make_float2(-S * t.y, S * t.x);
  }
#pragma unroll
  for (int p = 0; p < 16; p += 2) {
    float2 t = csub(a[p], a[p+1]); a[p] = cadd(a[p], a[p+1]); a[p+1] = t;
  }
  CSWAP(1, 8); CSWAP(2, 4); CSWAP(3, 12); CSWAP(5, 10); CSWAP(7, 14); CSWAP(11, 13);
}

// twiddle apply: a[k] *= w1^k. Powers via binary tree (depth 4) -> independent applies (ILP).
__device__ __forceinline__ void twchain(float2 a[16], float2 w1) {
  float2 w2 = cmul(w1, w1);
  float2 w3 = cmul(w2, w1);
  float2 w4 = cmul(w2, w2);
  float2 w5 = cmul(w3, w2);
  float2 w6 = cmul(w3, w3);
  float2 w7 = cmul(w4, w3);
  float2 w8 = cmul(w4, w4);
  float2 w9 = cmul(w5, w4);
  float2 w10 = cmul(w5, w5);
  float2 w11 = cmul(w6, w5);
  float2 w12 = cmul(w6, w6);
  float2 w13 = cmul(w7, w6);
  float2 w14 = cmul(w7, w7);
  float2 w15 = cmul(w8, w7);
  a[1]  = cmul(a[1],  w1);  a[2]  = cmul(a[2],  w2);  a[3]  = cmul(a[3],  w3);
  a[4]  = cmul(a[4],  w4);  a[5]  = cmul(a[5],  w5);  a[6]  = cmul(a[6],  w6);
  a[7]  = cmul(a[7],  w7);  a[8]  = cmul(a[8],  w8);  a[9]  = cmul(a[9],  w9);
  a[10] = cmul(a[10], w10); a[11] = cmul(a[11], w11); a[12] = cmul(a[12], w12);
  a[13] = cmul(a[13], w13); a[14] = cmul(a[14], w14); a[15] = cmul(a[15], w15);
}

// ===================== swizzled LDS transposes (FFT) =====================
__device__ __forceinline__ void lds_wA(float2* X, const float2 r[16], int tid) {
  int base = (tid & 15) * 16 + ((tid >> 4) ^ ((tid & 7) << 1));
#pragma unroll
  for (int i = 0; i < 16; ++i) X[base + i * 256] = r[i];
}
__device__ __forceinline__ void lds_wB(float2* X, const float2 r[16], int tid) {
#pragma unroll
  for (int i = 0; i < 16; ++i)
    X[((tid & 0xF0) + i) * 16 + ((tid & 15) ^ ((i & 7) << 1))] = r[i];
}
__device__ __forceinline__ void lds_rd(const float2* X, float2 r[16], int tid) {
  const float4* X4 = (const float4*)X;
#pragma unroll
  for (int p = 0; p < 8; ++p) {
    float4 v = X4[tid * 8 + (p ^ (tid & 7))];
    r[2 * p]     = make_float2(v.x, v.y);
    r[2 * p + 1] = make_float2(v.z, v.w);
  }
}

__device__ __forceinline__ void fft_fwd_hz(float2 r[16], float2* X, int tid, const float2* twg) {
  dft16<false, true>(r);
  twchain(r, twg[tid]);
  lds_wA(X, r, tid);
  __syncthreads();
  lds_rd(X, r, tid);
  dft16<false, false>(r);
  twchain(r, twg[(tid & 15) << 4]);
  __syncthreads();
  lds_wB(X, r, tid);
  __syncthreads();
  lds_rd(X, r, tid);
  dft16<false, false>(r);
}

__device__ __forceinline__ void fft_inv(float2 r[16], float2* X, int tid, const float2* twg) {
  dft16<true, false>(r);
  __syncthreads();
  lds_wB(X, r, tid);
  __syncthreads();
  lds_rd(X, r, tid);
  float2 wb = twg[(tid & 15) << 4];
  twchain(r, make_float2(wb.x, -wb.y));
  dft16<true, false>(r);
  __syncthreads();
  lds_wA(X, r, tid);
  __syncthreads();
  lds_rd(X, r, tid);
  float2 wa = twg[tid];
  twchain(r, make_float2(wa.x, -wa.y));
  dft16<true, false>(r);
}

// ===================== fused prep: ssmk + stats1 + twfill + wconv =====================
__global__ __launch_bounds__(256) void k_prep(const float* __restrict__ pw, u16* __restrict__ wb,
                                              const float* __restrict__ u, float* __restrict__ ps,
                                              float* __restrict__ pq,
                                              const float* __restrict__ Cp, const float* __restrict__ ldt,
                                              const float* __restrict__ lAr, const float* __restrict__ Aim,
                                              float2* __restrict__ kz, float2* __restrict__ tw) {
  __shared__ float4 sb[16][16], qb[16][16];
  int blk = blockIdx.x, tid = threadIdx.x;
  if (blk < PREP_SSMK) {
    // ---- ssmk (longest blocks first) ----
    int gid = blk * 256 + tid;   // 64*2048
    int h = gid & 2047;
    int j = gid >> 11;
    float dt = expf(ldt[h]);
    float accx = 0.f;
    float Ar0 = 0.f;
    for (int n = 0; n < 64; ++n) {
      float Ar = -expf(lAr[h * 64 + n]);
      float Ai = Aim[h * 64 + n];
      if (n == 0) Ar0 = Ar;
      float dAr = Ar * dt, dAi = Ai * dt;
      float er = expf(dAr);
      float s1, c1; sincosf(dAi, &s1, &c1);
      float emr = er * c1 - 1.0f, emi = er * s1;
      float inv = 1.0f / (Ar * Ar + Ai * Ai);
      float qr = (emr * Ar + emi * Ai) * inv;
      float qi = (emi * Ar - emr * Ai) * inv;
      float cr = Cp[(size_t)(h * 64 + n) * 2];
      float ci = Cp[(size_t)(h * 64 + n) * 2 + 1];
      float ccr = cr * qr - ci * qi;
      float cci = cr * qi + ci * qr;
      float ej = expf(dAr * (float)j);
      float sj, cj; sincosf(dAi * (float)j, &sj, &cj);
      accx += ccr * (ej * cj) - cci * (ej * sj);
    }
    float K = 2.0f * accx;
    float K2 = 2.0f * K * (Ar0 * (float)j * dt);
    kz[(size_t)j * L_ + h] = make_float2(K2, -K);        // pack K2 - i*K
  } else if (blk < PREP_SSMK + PREP_STATS1) {
    // ---- stats1 ----
    int blk2 = blk - PREP_SSMK;          // b*TCHUNK + q
    int b = blk2 >> 4, q = blk2 & 15;
    int c4 = tid & 15, g = tid >> 4;     // 16 groups x 8 t-steps
    const float4* u4 = (const float4*)(u + ((size_t)b * L_ + q * 128) * C_);
    float4 s = make_float4(0.f, 0.f, 0.f, 0.f), sq = s;
#pragma unroll
    for (int i = 0; i < 8; ++i) {
      float4 v = u4[(size_t)(g + 16 * i) * 16 + c4];
      s.x += v.x; s.y += v.y; s.z += v.z; s.w += v.w;
      sq.x += v.x * v.x; sq.y += v.y * v.y; sq.z += v.z * v.z; sq.w += v.w * v.w;
    }
    sb[g][c4] = s; qb[g][c4] = sq;
    __syncthreads();
    if (g == 0) {
      float4 S = sb[0][c4], Q = qb[0][c4];
#pragma unroll
      for (int k = 1; k < 16; ++k) {
        float4 a = sb[k][c4], d = qb[k][c4];
        S.x += a.x; S.y += a.y; S.z += a.z; S.w += a.w;
        Q.x += d.x; Q.y += d.y; Q.z += d.z; Q.w += d.w;
      }
      ((float4*)ps)[blk2 * 16 + c4] = S;
      ((float4*)pq)[blk2 * 16 + c4] = Q;
    }
  } else if (blk == PREP_SSMK + PREP_STATS1) {
    // ---- twfill ----
    int k = tid;
    double ang = -2.0 * 3.14159265358979323846 * (double)k / 4096.0;
    tw[k] = make_float2((float)cos(ang), (float)sin(ang));
  } else {
    // ---- wconv: interleaved (a,g) proj rows -> bf16 ----
    size_t idx = (size_t)(blk - (PREP_SSMK + PREP_STATS1 + 1)) * 256 + tid;
    int n = (int)(idx >> 11);
    int k = (int)(idx & 2047);
    int q = n >> 1;
    float v = 0.f;
    if (q < P_) {
      int p = (n & 1) ? (P_ + q) : q;
      v = pw[(size_t)p * L_ + k];
    }
    wb[idx] = f2bf(v);
  }
}

// ===================== fused: packT (inline mv) + fftk + stats2(for gemm) =====================
__global__ __launch_bounds__(256) void k_packfftk(const float* __restrict__ u, const float* __restrict__ Wn,
                                                  const float* __restrict__ lv,
                                                  const float* __restrict__ ps, const float* __restrict__ pq,
                                                  u32* __restrict__ zu,
                                                  const float2* __restrict__ kz, const float2* __restrict__ twg,
                                                  float2* __restrict__ G, float4* __restrict__ mv) {
  __shared__ __align__(16) char smem[33280];
  int blk = blockIdx.x, tid = threadIdx.x;
  if (blk < PF_PACK) {
    // ---- packT with inline per-block mv recompute (bit-identical to stats2) ----
    int b = blk >> 5;
    int t0 = (blk & 31) << 6;
    float4* mvs = (float4*)smem;           // transient, first 1 KB
    if (tid < 64) {
      float S = 0.f, Q = 0.f;
#pragma unroll
      for (int q = 0; q < 16; ++q) {
        S += ps[(size_t)(b * 16 + q) * 64 + tid];
        Q += pq[(size_t)(b * 16 + q) * 64 + tid];
      }
      float mean = S * (1.0f / 2048.0f);
      float var = (Q - S * S * (1.0f / 2048.0f)) * (1.0f / 2047.0f) + 1e-5f;
      float sv = sqrtf(var);
      mvs[tid] = make_float4(mean, sv, 1.0f / sv, 0.0f);
    }
    __syncthreads();
    int c = tid & 63, r = tid >> 6;
    float4 m = mvs[c];
    float stdn = sqrtf(__expf(lv[0]));
    __syncthreads();                       // mvs reads done before tile overwrites
    float2 (*tile)[65] = (float2(*)[65])smem;
#pragma unroll
    for (int i = 0; i < 16; ++i) {
      int t = t0 + i * 4 + r;
      size_t idx = ((size_t)b * L_ + t) * C_ + c;
      float uu = (u[idx] - m.x) * m.z;
      float ww = Wn[idx] * stdn;
      tile[i * 4 + r][c] = make_float2(uu, ww);
    }
    __syncthreads();
    int t = tid & 63, cb = tid >> 6;
#pragma unroll
    for (int i = 0; i < 16; ++i) {
      int c2 = i * 4 + cb;
      float2 v = tile[t][c2];
      zu[((size_t)(b * C_ + c2)) * L_ + t0 + t] = ((u32)f2bf(v.y) << 16) | (u32)f2bf(v.x);
    }
  } else if (blk < PF_PACK + PF_FFTK) {
    // ---- fftk: G[j] = FFT(K2 - iK)/4096 ----
    float2* X = (float2*)smem;
    int j = blk - PF_PACK;
    float2 r[16];
#pragma unroll
    for (int n2 = 0; n2 < 8; ++n2) r[n2] = kz[(size_t)j * L_ + n2 * 256 + tid];
    fft_fwd_hz(r, X, tid, twg);
    const float sc = 1.0f / 4096.0f;
#pragma unroll
    for (int k0 = 0; k0 < 16; ++k0)
      G[(size_t)j * NFFT + k0 * 256 + tid] = make_float2(r[k0].x * sc, r[k0].y * sc);
  } else {
    // ---- stats2: mv for the gemm epilogue (consumed 2 kernels later) ----
    int gid = (blk - (PF_PACK + PF_FFTK)) * 256 + tid;   // 8192
    int b = gid >> 6, c = gid & 63;
    float S = 0.f, Q = 0.f;
#pragma unroll
    for (int q = 0; q < 16; ++q) {
      S += ps[(size_t)(b * 16 + q) * 64 + c];
      Q += pq[(size_t)(b * 16 + q) * 64 + c];
    }
    float mean = S * (1.0f / 2048.0f);
    float var = (Q - S * S * (1.0f / 2048.0f)) * (1.0f / 2047.0f) + 1e-5f;
    float sv = sqrtf(var);
    mv[gid] = make_float4(mean, sv, 1.0f / sv, 0.0f);
  }
}

// ===================== main conv per row: y = Re(IFFT(FFT(z) .* G)) + un*D =====================
__global__ __launch_bounds__(256) void k_fftmain(const u32* __restrict__ zu, const float2* __restrict__ twg,
                                                 const float2* __restrict__ G, const float* __restrict__ Dv,
                                                 u16* __restrict__ yT) {
  __shared__ float2 X[NFFT];
  int row = blockIdx.x;           // b*64 + j
  int j = row & 63;
  int tid = threadIdx.x;
  float2 r[16];
  float usav[8];
#pragma unroll
  for (int n2 = 0; n2 < 8; ++n2) {
    u32 v = zu[(size_t)row * L_ + n2 * 256 + tid];
    float uu = bf2f_lo(v), ww = bf2f_hi(v);
    r[n2] = make_float2(uu, ww);
    usav[n2] = uu;
  }
  fft_fwd_hz(r, X, tid, twg);
  const float2* Gj = G + (size_t)j * NFFT;
#pragma unroll
  for (int k0 = 0; k0 < 16; ++k0) r[k0] = cmul(r[k0], Gj[k0 * 256 + tid]);
  fft_inv(r, X, tid, twg);
#pragma unroll
  for (int n2 = 8; n2 < 16; ++n2) {
    int t = (n2 - 8) * 256 + tid;
    float yv = r[n2].x + usav[n2 - 8] * Dv[t];
    yT[(size_t)row * L_ + t] = f2bf(yv);
  }
}

// ===================== bf16 MFMA GEMM — 3-deep counted-vmcnt pipeline + fused GLU epilogue ========
// C[M=8192][N=1536] = yT[M][K=2048] * Wb[N][K]^T, Wb cols interleaved (a,g) pairs.
// LDS 48 KB (3 x 16 KB tile-pairs) + aliased 16.9 KB epilogue buffer -> 49.2 KB, 3 blocks/CU
// (grid-imposed residency anyway). vmcnt(8) steady state: 2 tiles stay in flight across
// barriers -> ~2 K-steps (~500 cyc) of staging-latency tolerance.
__device__ __forceinline__ int lds_ix(int row, int slot) {
  return row * 32 + ((slot ^ ((row >> 1) & 3)) << 3);   // u16 units
}

__global__ __launch_bounds__(256) void k_gemm(const u16* __restrict__ A, const u16* __restrict__ B,
                                              const float* __restrict__ pb, const float4* __restrict__ mv,
                                              float* __restrict__ out) {
  __shared__ __align__(16) char gsm[49152];
  u16 (*As)[128 * 32] = (u16(*)[128 * 32])gsm;            // 3 x 8 KB
  u16 (*Bs)[128 * 32] = (u16(*)[128 * 32])(gsm + 24576);  // 3 x 8 KB
  float* ob = (float*)gsm;                                 // 16.9 KB, aliases As/Bs (epilogue only)
  const int K = L_;
  int tid = threadIdx.x;
  // bm-contiguous per-XCD map: XCD x owns bm in [8x, 8x+8) for all bn.
  int bid = blockIdx.x;
  int bm = (bid & 7) * 8 + ((bid >> 3) & 7);
  int bn = bid >> 6;
  int wave = tid >> 6, lane = tid & 63;
  int wm = (wave >> 1) << 6, wn = (wave & 1) << 6;
  int lr = lane & 15, lk = lane >> 4;
  // staging: wave w stages rows [w*32, w*32+32), 2 issues of 16 rows each.
  // LDS dest LINEAR; read side uses lds_ix swizzle -> global SOURCE col pre-swizzled (rule #21).
  int srow = wave * 32 + (lane >> 2);
  int sslot = lane & 3;
  int scol = (sslot ^ ((srow >> 1) & 3)) << 3;
  const u16* Ag = A + (size_t)(bm * 128 + srow) * K + scol;
  const u16* Bg = B + (size_t)(bn * 128 + srow) * K + scol;
  int woff = wave * 32 * 32;
  f32x4 acc[4][4] = {};
  // prologue: 3 tiles in flight (12 gload_lds / wave)
#pragma unroll
  for (int t = 0; t < 3; ++t) {
    GLOAD_LDS16(Ag + t * 32, &As[t][woff]);
    GLOAD_LDS16(Ag + t * 32 + (size_t)16 * K, &As[t][woff + 16 * 32]);
    GLOAD_LDS16(Bg + t * 32, &Bs[t][woff]);
    GLOAD_LDS16(Bg + t * 32 + (size_t)16 * K, &Bs[t][woff + 16 * 32]);
  }
  int cur = 0;
  for (int kt = 0; kt < K; kt += 32) {
    int rem = (K - 32 - kt) >> 5;                        // tiles possibly in flight beyond current
    if (rem >= 2)      asm volatile("s_waitcnt vmcnt(8)" ::: "memory");
    else if (rem == 1) asm volatile("s_waitcnt vmcnt(4)" ::: "memory");
    else               asm volatile("s_waitcnt vmcnt(0)" ::: "memory");
    __builtin_amdgcn_s_barrier();                        // all waves' stripes for tile kt landed
    short8 af[4], bf[4];
#pragma unroll
    for (int i2 = 0; i2 < 4; ++i2) af[i2] = *(const short8*)&As[cur][lds_ix(wm + i2 * 16 + lr, lk)];
#pragma unroll
    for (int j2 = 0; j2 < 4; ++j2) bf[j2] = *(const short8*)&Bs[cur][lds_ix(wn + j2 * 16 + lr, lk)];
#pragma unroll
    for (int i2 = 0; i2 < 4; ++i2)
#pragma unroll
      for (int j2 = 0; j2 < 4; ++j2)
        acc[i2][j2] = __builtin_amdgcn_mfma_f32_16x16x32_bf16(af[i2], bf[j2], acc[i2][j2], 0, 0, 0);
    __builtin_amdgcn_s_barrier();                        // all reads of buf[cur] consumed
    if (kt + 96 < K) {                                   // refill freed buffer with tile kt+96
      GLOAD_LDS16(Ag + kt + 96, &As[cur][woff]);
      GLOAD_LDS16(Ag + kt + 96 + (size_t)16 * K, &As[cur][woff + 16 * 32]);
      GLOAD_LDS16(Bg + kt + 96, &Bs[cur][woff]);
      GLOAD_LDS16(Bg + kt + 96 + (size_t)16 * K, &Bs[cur][woff + 16 * 32]);
    }
    cur = (cur == 2) ? 0 : cur + 1;
  }
  // ======== fused epilogue (ob aliases As/Bs; barrier below makes the WAR safe) ========
  int col_lo = wn + lr;                      // + j2*16
  for (int chunk = 0; chunk < 2; ++chunk) {
    __syncthreads();                         // K-loop LDS reads / prev chunk reads complete
#pragma unroll
    for (int j2c = 0; j2c < 2; ++j2c) {
      int j2 = chunk * 2 + j2c;
      int col = col_lo + j2 * 16;            // 0..127
      int nglob = bn * 128 + col;
      int q = nglob >> 1;
      float bias = 0.f;
      if (q < P_) bias = pb[(nglob & 1) ? (P_ + q) : q];
      int qloc = col >> 1;
      int s = (qloc & 15) | ((qloc >> 5) << 4);   // chunk-local slot 0..31
#pragma unroll
      for (int i2 = 0; i2 < 4; ++i2) {
        int row = wm + i2 * 16 + lk * 4;
        float res[4];
#pragma unroll
        for (int rgi = 0; rgi < 4; ++rgi) {
          float val = acc[i2][j2][rgi] + bias;
          float other = __shfl_xor(val, 1);
          float4 m = mv[bm * 128 + row + rgi];
          res[rgi] = val * (1.0f / (1.0f + __expf(-other))) * m.y + m.x;
        }
        if (!(lane & 1)) {
          *(float4*)&ob[s * 132 + row] = make_float4(res[0], res[1], res[2], res[3]);
        }
      }
    }
    __syncthreads();
    int c = tid & 63, sl4 = tid >> 6;
    for (int rd = 0; rd < 16; ++rd) {
      int slice = rd * 4 + sl4;
      int s = slice >> 1, bb = slice & 1;
      int qloc = (s & 15) + chunk * 16 + ((s >> 4) << 5);
      int qglob = bn * 64 + qloc;
      if (qglob < P_) {
        int bg = bm * 2 + bb;
        out[((size_t)bg * P_ + qglob) * 64 + c] = ob[s * 132 + bb * 64 + c];
      }
    }
  }
}

extern "C" void kernel_launch(void* const* d_in, const int* in_sizes, int n_in,
                              void* d_out, int out_size, void* d_ws, size_t ws_size,
                              hipStream_t stream) {
  const float* u   = (const float*)d_in[0];
  const float* Wn  = (const float*)d_in[4];
  const float* Dv  = (const float*)d_in[5];
  const float* lv  = (const float*)d_in[6];
  const float* Cp  = (const float*)d_in[7];
  const float* ldt = (const float*)d_in[8];
  const float* lAr = (const float*)d_in[9];
  const float* Aim = (const float*)d_in[10];
  const float* pw  = (const float*)d_in[11];
  const float* pb  = (const float*)d_in[12];
  float* out = (float*)d_out;
  char* ws = (char*)d_ws;

  // workspace layout (bytes)
  float2* tw = (float2*)(ws + 0);                  // 2 KB
  float4* mv = (float4*)(ws + (64 << 10));         // 128 KB  -> ends 192 KB
  float2* G  = (float2*)(ws + (1 << 20));          // 2 MB    -> ends 3 MB
  float2* kz = (float2*)(ws + (3 << 20));          // 1 MB    -> ends 4 MB
  u16*    Wb = (u16*)   (ws + (4 << 20));          // 6 MB    -> ends 10 MB
  float*  ps = (float*) (ws + (10 << 20));         // 512 KB
  float*  pq = (float*) (ws + (10 << 20) + (512 << 10)); // 512 KB -> ends 11 MB
  u16*    yT = (u16*)   (ws + (16 << 20));         // 32 MB   -> ends 48 MB
  u32*    zu = (u32*)   (ws + ((size_t)48 << 20)); // 64 MB   -> ends 112 MB

  k_prep<<<PREP_NB, 256, 0, stream>>>(pw, Wb, u, ps, pq, Cp, ldt, lAr, Aim, kz, tw);
  k_packfftk<<<PF_NB, 256, 0, stream>>>(u, Wn, lv, ps, pq, zu, kz, tw, G, mv);
  k_fftmain<<<NROW, 256, 0, stream>>>(zu, tw, G, Dv, yT);
  k_gemm<<<64 * (NPAD / 128), 256, 0, stream>>>(yT, Wb, pb, mv, out);
}

// Round 16
// 307.160 us; speedup vs baseline: 1.0678x; 1.0093x over previous
//
#include <hip/hip_runtime.h>
#include <math.h>

typedef unsigned short u16;
typedef unsigned int u32;
typedef __attribute__((ext_vector_type(8))) short short8;
typedef __attribute__((ext_vector_type(4))) float f32x4;

// Problem constants
#define B_   128
#define L_   2048
#define C_   64
#define P_   720
#define P2_  1440
#define NPAD 1536     // proj cols padded to multiple of 128 (interleaved a/g)
#define NFFT 4096
#define NROW (B_*C_)  // 8192
#define TCHUNK 16     // time chunks for stats phase 1

// prep-kernel block ranges (longest blocks first)
#define PREP_SSMK   512
#define PREP_STATS1 2048
#define PREP_NB     (PREP_SSMK + PREP_STATS1 + 1 + (NPAD * L_) / 256)
// packfftk ranges
#define PF_PACK  4096
#define PF_FFTK  64
#define PF_NB    (PF_PACK + PF_FFTK + 32)

// global -> LDS direct staging, 16 B per lane; LDS dest = uniform base + lane*16
#define GLOAD_LDS16(g, l) __builtin_amdgcn_global_load_lds( \
    (const __attribute__((address_space(1))) unsigned int*)(g), \
    (__attribute__((address_space(3))) unsigned int*)(l), 16, 0, 0)

__device__ __forceinline__ u16 f2bf(float f) {
  union { float f; unsigned u; } x; x.f = f;
  unsigned r = x.u + 0x7fffu + ((x.u >> 16) & 1u);
  return (u16)(r >> 16);
}
__device__ __forceinline__ float bf2f_lo(u32 v) {
  union { unsigned u; float f; } x; x.u = v << 16; return x.f;
}
__device__ __forceinline__ float bf2f_hi(u32 v) {
  union { unsigned u; float f; } x; x.u = v & 0xffff0000u; return x.f;
}

__device__ __forceinline__ float2 cmul(float2 a, float2 b) {
  return make_float2(a.x * b.x - a.y * b.y, a.x * b.y + a.y * b.x);
}
__device__ __forceinline__ float2 cadd(float2 a, float2 b) { return make_float2(a.x + b.x, a.y + b.y); }
__device__ __forceinline__ float2 csub(float2 a, float2 b) { return make_float2(a.x - b.x, a.y - b.y); }

#define CSWAP(i, j) { float2 tt = a[i]; a[i] = a[j]; a[j] = tt; }

// ===================== 16-point DFT in registers =====================
template<bool INV, bool HZ>
__device__ __forceinline__ void dft16(float2 a[16]) {
  const float S  = INV ? 1.f : -1.f;
  const float c1 = 0.9238795325112867f, s1 = 0.3826834323650898f, q2 = 0.7071067811865476f;
  const float2 W1 = make_float2( c1, S * s1), W2 = make_float2( q2, S * q2), W3 = make_float2( s1, S * c1);
  const float2 W5 = make_float2(-s1, S * c1), W6 = make_float2(-q2, S * q2), W7 = make_float2(-c1, S * s1);
  if (HZ) {
    a[8]  = a[0];
    a[9]  = cmul(a[1], W1);
    a[10] = cmul(a[2], W2);
    a[11] = cmul(a[3], W3);
    a[12] = make_float2(-S * a[4].y, S * a[4].x);
    a[13] = cmul(a[5], W5);
    a[14] = cmul(a[6], W6);
    a[15] = cmul(a[7], W7);
  } else {
    float2 t;
    t = csub(a[0], a[8]);  a[0] = cadd(a[0], a[8]);  a[8]  = t;
    t = csub(a[1], a[9]);  a[1] = cadd(a[1], a[9]);  a[9]  = cmul(t, W1);
    t = csub(a[2], a[10]); a[2] = cadd(a[2], a[10]); a[10] = cmul(t, W2);
    t = csub(a[3], a[11]); a[3] = cadd(a[3], a[11]); a[11] = cmul(t, W3);
    t = csub(a[4], a[12]); a[4] = cadd(a[4], a[12]); a[12] = make_float2(-S * t.y, S * t.x);
    t = csub(a[5], a[13]); a[5] = cadd(a[5], a[13]); a[13] = cmul(t, W5);
    t = csub(a[6], a[14]); a[6] = cadd(a[6], a[14]); a[14] = cmul(t, W6);
    t = csub(a[7], a[15]); a[7] = cadd(a[7], a[15]); a[15] = cmul(t, W7);
  }
#pragma unroll
  for (int h = 0; h < 16; h += 8) {
    float2 t;
    t = csub(a[h+0], a[h+4]); a[h+0] = cadd(a[h+0], a[h+4]); a[h+4] = t;
    t = csub(a[h+1], a[h+5]); a[h+1] = cadd(a[h+1], a[h+5]); a[h+5] = cmul(t, W2);
    t = csub(a[h+2], a[h+6]); a[h+2] = cadd(a[h+2], a[h+6]); a[h+6] = make_float2(-S * t.y, S * t.x);
    t = csub(a[h+3], a[h+7]); a[h+3] = cadd(a[h+3], a[h+7]); a[h+7] = cmul(t, W6);
  }
#pragma unroll
  for (int q = 0; q < 16; q += 4) {
    float2 t;
    t = csub(a[q+0], a[q+2]); a[q+0] = cadd(a[q+0], a[q+2]); a[q+2] = t;
    t = csub(a[q+1], a[q+3]); a[q+1] = cadd(a[q+1], a[q+3]); a[q+3] = make_float2(-S * t.y, S * t.x);
  }
#pragma unroll
  for (int p = 0; p < 16; p += 2) {
    float2 t = csub(a[p], a[p+1]); a[p] = cadd(a[p], a[p+1]); a[p+1] = t;
  }
  CSWAP(1, 8); CSWAP(2, 4); CSWAP(3, 12); CSWAP(5, 10); CSWAP(7, 14); CSWAP(11, 13);
}

// twiddle apply: a[k] *= w1^k. Powers via binary tree (depth 4) -> independent applies (ILP).
__device__ __forceinline__ void twchain(float2 a[16], float2 w1) {
  float2 w2 = cmul(w1, w1);
  float2 w3 = cmul(w2, w1);
  float2 w4 = cmul(w2, w2);
  float2 w5 = cmul(w3, w2);
  float2 w6 = cmul(w3, w3);
  float2 w7 = cmul(w4, w3);
  float2 w8 = cmul(w4, w4);
  float2 w9 = cmul(w5, w4);
  float2 w10 = cmul(w5, w5);
  float2 w11 = cmul(w6, w5);
  float2 w12 = cmul(w6, w6);
  float2 w13 = cmul(w7, w6);
  float2 w14 = cmul(w7, w7);
  float2 w15 = cmul(w8, w7);
  a[1]  = cmul(a[1],  w1);  a[2]  = cmul(a[2],  w2);  a[3]  = cmul(a[3],  w3);
  a[4]  = cmul(a[4],  w4);  a[5]  = cmul(a[5],  w5);  a[6]  = cmul(a[6],  w6);
  a[7]  = cmul(a[7],  w7);  a[8]  = cmul(a[8],  w8);  a[9]  = cmul(a[9],  w9);
  a[10] = cmul(a[10], w10); a[11] = cmul(a[11], w11); a[12] = cmul(a[12], w12);
  a[13] = cmul(a[13], w13); a[14] = cmul(a[14], w14); a[15] = cmul(a[15], w15);
}

// ===================== swizzled LDS transposes (FFT) =====================
__device__ __forceinline__ void lds_wA(float2* X, const float2 r[16], int tid) {
  int base = (tid & 15) * 16 + ((tid >> 4) ^ ((tid & 7) << 1));
#pragma unroll
  for (int i = 0; i < 16; ++i) X[base + i * 256] = r[i];
}
__device__ __forceinline__ void lds_wB(float2* X, const float2 r[16], int tid) {
#pragma unroll
  for (int i = 0; i < 16; ++i)
    X[((tid & 0xF0) + i) * 16 + ((tid & 15) ^ ((i & 7) << 1))] = r[i];
}
__device__ __forceinline__ void lds_rd(const float2* X, float2 r[16], int tid) {
  const float4* X4 = (const float4*)X;
#pragma unroll
  for (int p = 0; p < 8; ++p) {
    float4 v = X4[tid * 8 + (p ^ (tid & 7))];
    r[2 * p]     = make_float2(v.x, v.y);
    r[2 * p + 1] = make_float2(v.z, v.w);
  }
}

__device__ __forceinline__ void fft_fwd_hz(float2 r[16], float2* X, int tid, const float2* twg) {
  dft16<false, true>(r);
  twchain(r, twg[tid]);
  lds_wA(X, r, tid);
  __syncthreads();
  lds_rd(X, r, tid);
  dft16<false, false>(r);
  twchain(r, twg[(tid & 15) << 4]);
  __syncthreads();
  lds_wB(X, r, tid);
  __syncthreads();
  lds_rd(X, r, tid);
  dft16<false, false>(r);
}

__device__ __forceinline__ void fft_inv(float2 r[16], float2* X, int tid, const float2* twg) {
  dft16<true, false>(r);
  __syncthreads();
  lds_wB(X, r, tid);
  __syncthreads();
  lds_rd(X, r, tid);
  float2 wb = twg[(tid & 15) << 4];
  twchain(r, make_float2(wb.x, -wb.y));
  dft16<true, false>(r);
  __syncthreads();
  lds_wA(X, r, tid);
  __syncthreads();
  lds_rd(X, r, tid);
  float2 wa = twg[tid];
  twchain(r, make_float2(wa.x, -wa.y));
  dft16<true, false>(r);
}

// ===================== fused prep: ssmk + stats1 + twfill + wconv =====================
__global__ __launch_bounds__(256) void k_prep(const float* __restrict__ pw, u16* __restrict__ wb,
                                              const float* __restrict__ u, float* __restrict__ ps,
                                              float* __restrict__ pq,
                                              const float* __restrict__ Cp, const float* __restrict__ ldt,
                                              const float* __restrict__ lAr, const float* __restrict__ Aim,
                                              float2* __restrict__ kz, float2* __restrict__ tw) {
  __shared__ float4 sb[16][16], qb[16][16];
  int blk = blockIdx.x, tid = threadIdx.x;
  if (blk < PREP_SSMK) {
    // ---- ssmk (longest blocks first) ----
    int gid = blk * 256 + tid;   // 64*2048
    int h = gid & 2047;
    int j = gid >> 11;
    float dt = expf(ldt[h]);
    float accx = 0.f;
    float Ar0 = 0.f;
    for (int n = 0; n < 64; ++n) {
      float Ar = -expf(lAr[h * 64 + n]);
      float Ai = Aim[h * 64 + n];
      if (n == 0) Ar0 = Ar;
      float dAr = Ar * dt, dAi = Ai * dt;
      float er = expf(dAr);
      float s1, c1; sincosf(dAi, &s1, &c1);
      float emr = er * c1 - 1.0f, emi = er * s1;
      float inv = 1.0f / (Ar * Ar + Ai * Ai);
      float qr = (emr * Ar + emi * Ai) * inv;
      float qi = (emi * Ar - emr * Ai) * inv;
      float cr = Cp[(size_t)(h * 64 + n) * 2];
      float ci = Cp[(size_t)(h * 64 + n) * 2 + 1];
      float ccr = cr * qr - ci * qi;
      float cci = cr * qi + ci * qr;
      float ej = expf(dAr * (float)j);
      float sj, cj; sincosf(dAi * (float)j, &sj, &cj);
      accx += ccr * (ej * cj) - cci * (ej * sj);
    }
    float K = 2.0f * accx;
    float K2 = 2.0f * K * (Ar0 * (float)j * dt);
    kz[(size_t)j * L_ + h] = make_float2(K2, -K);        // pack K2 - i*K
  } else if (blk < PREP_SSMK + PREP_STATS1) {
    // ---- stats1 ----
    int blk2 = blk - PREP_SSMK;          // b*TCHUNK + q
    int b = blk2 >> 4, q = blk2 & 15;
    int c4 = tid & 15, g = tid >> 4;     // 16 groups x 8 t-steps
    const float4* u4 = (const float4*)(u + ((size_t)b * L_ + q * 128) * C_);
    float4 s = make_float4(0.f, 0.f, 0.f, 0.f), sq = s;
#pragma unroll
    for (int i = 0; i < 8; ++i) {
      float4 v = u4[(size_t)(g + 16 * i) * 16 + c4];
      s.x += v.x; s.y += v.y; s.z += v.z; s.w += v.w;
      sq.x += v.x * v.x; sq.y += v.y * v.y; sq.z += v.z * v.z; sq.w += v.w * v.w;
    }
    sb[g][c4] = s; qb[g][c4] = sq;
    __syncthreads();
    if (g == 0) {
      float4 S = sb[0][c4], Q = qb[0][c4];
#pragma unroll
      for (int k = 1; k < 16; ++k) {
        float4 a = sb[k][c4], d = qb[k][c4];
        S.x += a.x; S.y += a.y; S.z += a.z; S.w += a.w;
        Q.x += d.x; Q.y += d.y; Q.z += d.z; Q.w += d.w;
      }
      ((float4*)ps)[blk2 * 16 + c4] = S;
      ((float4*)pq)[blk2 * 16 + c4] = Q;
    }
  } else if (blk == PREP_SSMK + PREP_STATS1) {
    // ---- twfill ----
    int k = tid;
    double ang = -2.0 * 3.14159265358979323846 * (double)k / 4096.0;
    tw[k] = make_float2((float)cos(ang), (float)sin(ang));
  } else {
    // ---- wconv: interleaved (a,g) proj rows -> bf16 ----
    size_t idx = (size_t)(blk - (PREP_SSMK + PREP_STATS1 + 1)) * 256 + tid;
    int n = (int)(idx >> 11);
    int k = (int)(idx & 2047);
    int q = n >> 1;
    float v = 0.f;
    if (q < P_) {
      int p = (n & 1) ? (P_ + q) : q;
      v = pw[(size_t)p * L_ + k];
    }
    wb[idx] = f2bf(v);
  }
}

// ===================== fused: packT (inline mv) + fftk + stats2(for gemm) =====================
__global__ __launch_bounds__(256) void k_packfftk(const float* __restrict__ u, const float* __restrict__ Wn,
                                                  const float* __restrict__ lv,
                                                  const float* __restrict__ ps, const float* __restrict__ pq,
                                                  u32* __restrict__ zu,
                                                  const float2* __restrict__ kz, const float2* __restrict__ twg,
                                                  float2* __restrict__ G, float4* __restrict__ mv) {
  __shared__ __align__(16) char smem[33280];
  int blk = blockIdx.x, tid = threadIdx.x;
  if (blk < PF_PACK) {
    // ---- packT with inline per-block mv recompute (bit-identical to stats2) ----
    int b = blk >> 5;
    int t0 = (blk & 31) << 6;
    float4* mvs = (float4*)smem;           // transient, first 1 KB
    if (tid < 64) {
      float S = 0.f, Q = 0.f;
#pragma unroll
      for (int q = 0; q < 16; ++q) {
        S += ps[(size_t)(b * 16 + q) * 64 + tid];
        Q += pq[(size_t)(b * 16 + q) * 64 + tid];
      }
      float mean = S * (1.0f / 2048.0f);
      float var = (Q - S * S * (1.0f / 2048.0f)) * (1.0f / 2047.0f) + 1e-5f;
      float sv = sqrtf(var);
      mvs[tid] = make_float4(mean, sv, 1.0f / sv, 0.0f);
    }
    __syncthreads();
    int c = tid & 63, r = tid >> 6;
    float4 m = mvs[c];
    float stdn = sqrtf(__expf(lv[0]));
    __syncthreads();                       // mvs reads done before tile overwrites
    float2 (*tile)[65] = (float2(*)[65])smem;
#pragma unroll
    for (int i = 0; i < 16; ++i) {
      int t = t0 + i * 4 + r;
      size_t idx = ((size_t)b * L_ + t) * C_ + c;
      float uu = (u[idx] - m.x) * m.z;
      float ww = Wn[idx] * stdn;
      tile[i * 4 + r][c] = make_float2(uu, ww);
    }
    __syncthreads();
    int t = tid & 63, cb = tid >> 6;
#pragma unroll
    for (int i = 0; i < 16; ++i) {
      int c2 = i * 4 + cb;
      float2 v = tile[t][c2];
      zu[((size_t)(b * C_ + c2)) * L_ + t0 + t] = ((u32)f2bf(v.y) << 16) | (u32)f2bf(v.x);
    }
  } else if (blk < PF_PACK + PF_FFTK) {
    // ---- fftk: G[j] = FFT(K2 - iK)/4096 ----
    float2* X = (float2*)smem;
    int j = blk - PF_PACK;
    float2 r[16];
#pragma unroll
    for (int n2 = 0; n2 < 8; ++n2) r[n2] = kz[(size_t)j * L_ + n2 * 256 + tid];
    fft_fwd_hz(r, X, tid, twg);
    const float sc = 1.0f / 4096.0f;
#pragma unroll
    for (int k0 = 0; k0 < 16; ++k0)
      G[(size_t)j * NFFT + k0 * 256 + tid] = make_float2(r[k0].x * sc, r[k0].y * sc);
  } else {
    // ---- stats2: mv for the gemm epilogue (consumed 2 kernels later) ----
    int gid = (blk - (PF_PACK + PF_FFTK)) * 256 + tid;   // 8192
    int b = gid >> 6, c = gid & 63;
    float S = 0.f, Q = 0.f;
#pragma unroll
    for (int q = 0; q < 16; ++q) {
      S += ps[(size_t)(b * 16 + q) * 64 + c];
      Q += pq[(size_t)(b * 16 + q) * 64 + c];
    }
    float mean = S * (1.0f / 2048.0f);
    float var = (Q - S * S * (1.0f / 2048.0f)) * (1.0f / 2047.0f) + 1e-5f;
    float sv = sqrtf(var);
    mv[gid] = make_float4(mean, sv, 1.0f / sv, 0.0f);
  }
}

// ===================== main conv per row: y = Re(IFFT(FFT(z) .* G)) + un*D =====================
__global__ __launch_bounds__(256) void k_fftmain(const u32* __restrict__ zu, const float2* __restrict__ twg,
                                                 const float2* __restrict__ G, const float* __restrict__ Dv,
                                                 u16* __restrict__ yT) {
  __shared__ float2 X[NFFT];
  int row = blockIdx.x;           // b*64 + j
  int j = row & 63;
  int tid = threadIdx.x;
  float2 r[16];
  float usav[8];
#pragma unroll
  for (int n2 = 0; n2 < 8; ++n2) {
    u32 v = zu[(size_t)row * L_ + n2 * 256 + tid];
    float uu = bf2f_lo(v), ww = bf2f_hi(v);
    r[n2] = make_float2(uu, ww);
    usav[n2] = uu;
  }
  fft_fwd_hz(r, X, tid, twg);
  const float2* Gj = G + (size_t)j * NFFT;
#pragma unroll
  for (int k0 = 0; k0 < 16; ++k0) r[k0] = cmul(r[k0], Gj[k0 * 256 + tid]);
  fft_inv(r, X, tid, twg);
#pragma unroll
  for (int n2 = 8; n2 < 16; ++n2) {
    int t = (n2 - 8) * 256 + tid;
    float yv = r[n2].x + usav[n2 - 8] * Dv[t];
    yT[(size_t)row * L_ + t] = f2bf(yv);
  }
}

// ===================== bf16 MFMA GEMM — 3-buffer SINGLE-barrier 2-phase + fused GLU epilogue ======
// C[M=8192][N=1536] = yT[M][K=2048] * Wb[N][K]^T, Wb cols interleaved (a,g) pairs.
// T3 minimum template: per K-step { vmcnt(4); s_barrier; stage(t+2); ds_read(t); 16 MFMA }.
// One barrier per step (64 vs 128): the 3rd buffer legalizes it — stage target buf[(t+2)%3]
// was read at step t-1, and this step's barrier proves all waves finished those reads.
__device__ __forceinline__ int lds_ix(int row, int slot) {
  return row * 32 + ((slot ^ ((row >> 1) & 3)) << 3);   // u16 units
}

__global__ __launch_bounds__(256) void k_gemm(const u16* __restrict__ A, const u16* __restrict__ B,
                                              const float* __restrict__ pb, const float4* __restrict__ mv,
                                              float* __restrict__ out) {
  __shared__ __align__(16) char gsm[49152];
  u16 (*As)[128 * 32] = (u16(*)[128 * 32])gsm;            // 3 x 8 KB
  u16 (*Bs)[128 * 32] = (u16(*)[128 * 32])(gsm + 24576);  // 3 x 8 KB
  float* ob = (float*)gsm;                                 // 16.9 KB, aliases As/Bs (epilogue only)
  const int K = L_;
  int tid = threadIdx.x;
  // bm-contiguous per-XCD map: XCD x owns bm in [8x, 8x+8) for all bn.
  int bid = blockIdx.x;
  int bm = (bid & 7) * 8 + ((bid >> 3) & 7);
  int bn = bid >> 6;
  int wave = tid >> 6, lane = tid & 63;
  int wm = (wave >> 1) << 6, wn = (wave & 1) << 6;
  int lr = lane & 15, lk = lane >> 4;
  // staging: wave w stages rows [w*32, w*32+32), 2 issues of 16 rows each.
  // LDS dest LINEAR; read side uses lds_ix swizzle -> global SOURCE col pre-swizzled (rule #21).
  int srow = wave * 32 + (lane >> 2);
  int sslot = lane & 3;
  int scol = (sslot ^ ((srow >> 1) & 3)) << 3;
  const u16* Ag = A + (size_t)(bm * 128 + srow) * K + scol;
  const u16* Bg = B + (size_t)(bn * 128 + srow) * K + scol;
  int woff = wave * 32 * 32;
  f32x4 acc[4][4] = {};
  // prologue: 2 tiles in flight (8 gload_lds / wave)
#pragma unroll
  for (int t = 0; t < 2; ++t) {
    GLOAD_LDS16(Ag + t * 32, &As[t][woff]);
    GLOAD_LDS16(Ag + t * 32 + (size_t)16 * K, &As[t][woff + 16 * 32]);
    GLOAD_LDS16(Bg + t * 32, &Bs[t][woff]);
    GLOAD_LDS16(Bg + t * 32 + (size_t)16 * K, &Bs[t][woff + 16 * 32]);
  }
  int cur = 0;
  for (int kt = 0; kt < K; kt += 32) {
    if (kt + 32 < K) asm volatile("s_waitcnt vmcnt(4)" ::: "memory");  // tile kt landed (per-wave)
    else             asm volatile("s_waitcnt vmcnt(0)" ::: "memory");  // last tile: drain
    __builtin_amdgcn_s_barrier();        // (a) all stripes of tile kt landed
                                         // (b) all waves' reads of buf[(kt/32+2)%3] (step kt-32) done
    if (kt + 64 < K) {                   // stage tile kt+64 into the freed buffer
      int nb = cur + 2; if (nb >= 3) nb -= 3;
      GLOAD_LDS16(Ag + kt + 64, &As[nb][woff]);
      GLOAD_LDS16(Ag + kt + 64 + (size_t)16 * K, &As[nb][woff + 16 * 32]);
      GLOAD_LDS16(Bg + kt + 64, &Bs[nb][woff]);
      GLOAD_LDS16(Bg + kt + 64 + (size_t)16 * K, &Bs[nb][woff + 16 * 32]);
    }
    short8 af[4], bf[4];
#pragma unroll
    for (int i2 = 0; i2 < 4; ++i2) af[i2] = *(const short8*)&As[cur][lds_ix(wm + i2 * 16 + lr, lk)];
#pragma unroll
    for (int j2 = 0; j2 < 4; ++j2) bf[j2] = *(const short8*)&Bs[cur][lds_ix(wn + j2 * 16 + lr, lk)];
#pragma unroll
    for (int i2 = 0; i2 < 4; ++i2)
#pragma unroll
      for (int j2 = 0; j2 < 4; ++j2)
        acc[i2][j2] = __builtin_amdgcn_mfma_f32_16x16x32_bf16(af[i2], bf[j2], acc[i2][j2], 0, 0, 0);
    cur = (cur == 2) ? 0 : cur + 1;
  }
  // ======== fused epilogue (ob aliases As/Bs; barrier below makes the WAR safe) ========
  int col_lo = wn + lr;                      // + j2*16
  for (int chunk = 0; chunk < 2; ++chunk) {
    __syncthreads();                         // K-loop LDS reads / prev chunk reads complete
#pragma unroll
    for (int j2c = 0; j2c < 2; ++j2c) {
      int j2 = chunk * 2 + j2c;
      int col = col_lo + j2 * 16;            // 0..127
      int nglob = bn * 128 + col;
      int q = nglob >> 1;
      float bias = 0.f;
      if (q < P_) bias = pb[(nglob & 1) ? (P_ + q) : q];
      int qloc = col >> 1;
      int s = (qloc & 15) | ((qloc >> 5) << 4);   // chunk-local slot 0..31
#pragma unroll
      for (int i2 = 0; i2 < 4; ++i2) {
        int row = wm + i2 * 16 + lk * 4;
        float res[4];
#pragma unroll
        for (int rgi = 0; rgi < 4; ++rgi) {
          float val = acc[i2][j2][rgi] + bias;
          float other = __shfl_xor(val, 1);
          float4 m = mv[bm * 128 + row + rgi];
          res[rgi] = val * (1.0f / (1.0f + __expf(-other))) * m.y + m.x;
        }
        if (!(lane & 1)) {
          *(float4*)&ob[s * 132 + row] = make_float4(res[0], res[1], res[2], res[3]);
        }
      }
    }
    __syncthreads();
    int c = tid & 63, sl4 = tid >> 6;
    for (int rd = 0; rd < 16; ++rd) {
      int slice = rd * 4 + sl4;
      int s = slice >> 1, bb = slice & 1;
      int qloc = (s & 15) + chunk * 16 + ((s >> 4) << 5);
      int qglob = bn * 64 + qloc;
      if (qglob < P_) {
        int bg = bm * 2 + bb;
        out[((size_t)bg * P_ + qglob) * 64 + c] = ob[s * 132 + bb * 64 + c];
      }
    }
  }
}

extern "C" void kernel_launch(void* const* d_in, const int* in_sizes, int n_in,
                              void* d_out, int out_size, void* d_ws, size_t ws_size,
                              hipStream_t stream) {
  const float* u   = (const float*)d_in[0];
  const float* Wn  = (const float*)d_in[4];
  const float* Dv  = (const float*)d_in[5];
  const float* lv  = (const float*)d_in[6];
  const float* Cp  = (const float*)d_in[7];
  const float* ldt = (const float*)d_in[8];
  const float* lAr = (const float*)d_in[9];
  const float* Aim = (const float*)d_in[10];
  const float* pw  = (const float*)d_in[11];
  const float* pb  = (const float*)d_in[12];
  float* out = (float*)d_out;
  char* ws = (char*)d_ws;

  // workspace layout (bytes)
  float2* tw = (float2*)(ws + 0);                  // 2 KB
  float4* mv = (float4*)(ws + (64 << 10));         // 128 KB  -> ends 192 KB
  float2* G  = (float2*)(ws + (1 << 20));          // 2 MB    -> ends 3 MB
  float2* kz = (float2*)(ws + (3 << 20));          // 1 MB    -> ends 4 MB
  u16*    Wb = (u16*)   (ws + (4 << 20));          // 6 MB    -> ends 10 MB
  float*  ps = (float*) (ws + (10 << 20));         // 512 KB
  float*  pq = (float*) (ws + (10 << 20) + (512 << 10)); // 512 KB -> ends 11 MB
  u16*    yT = (u16*)   (ws + (16 << 20));         // 32 MB   -> ends 48 MB
  u32*    zu = (u32*)   (ws + ((size_t)48 << 20)); // 64 MB   -> ends 112 MB

  k_prep<<<PREP_NB, 256, 0, stream>>>(pw, Wb, u, ps, pq, Cp, ldt, lAr, Aim, kz, tw);
  k_packfftk<<<PF_NB, 256, 0, stream>>>(u, Wn, lv, ps, pq, zu, kz, tw, G, mv);
  k_fftmain<<<NROW, 256, 0, stream>>>(zu, tw, G, Dv, yT);
  k_gemm<<<64 * (NPAD / 128), 256, 0, stream>>>(yT, Wb, pb, mv, out);
}